// Round 10
// baseline (233.927 us; speedup 1.0000x reference)
//
#include <hip/hip_runtime.h>
#include <hip/hip_bf16.h>

// GCN 2-layer encoder. R10: XCD-aware column-split gathers (tile = f(blockIdx%8)
// pins each XCD to a 3.2MB column slice of g -> L2-resident, random reads become
// L2 hits); binA single edge-list read via register stash. Build/GEMMs from R9.
// out[d] = dinv[d] * sum_{s in N(d) U {d}} g[s] + b,  g[s] = dinv[s]*(in@W)[s]

constexpr int FIN = 128;
constexpr int HID = 128;
constexpr int FOUT = 64;
constexpr int CAP = 48;     // adjacency slots per node
constexpr int NPB = 98;     // nodes per bucket
constexpr int BCAP = 3072;  // pairs per bucket region
constexpr int OVF_MAX = 65536;

typedef __attribute__((ext_vector_type(8))) short s16x8;
typedef __attribute__((ext_vector_type(4))) float f32x4;

static __device__ __forceinline__ float bf2f(__hip_bfloat16 v) { return __bfloat162float(v); }
static __device__ __forceinline__ float lo2f(unsigned u) { union { unsigned i; float f; } c; c.i = u << 16; return c.f; }
static __device__ __forceinline__ float hi2f(unsigned u) { union { unsigned i; float f; } c; c.i = u & 0xffff0000u; return c.f; }
static __device__ __forceinline__ unsigned short f2bfu(float f) {
    __hip_bfloat16 h = __float2bfloat16(f);
    union { __hip_bfloat16 h; unsigned short u; } c; c.h = h; return c.u;
}
static __device__ __forceinline__ unsigned pack2(float a, float b) {
    return (unsigned)f2bfu(a) | ((unsigned)f2bfu(b) << 16);
}
static __device__ __forceinline__ void acc_add(float* acc, uint4 v) {
    acc[0] += lo2f(v.x); acc[1] += hi2f(v.x);
    acc[2] += lo2f(v.y); acc[3] += hi2f(v.y);
    acc[4] += lo2f(v.z); acc[5] += hi2f(v.z);
    acc[6] += lo2f(v.w); acc[7] += hi2f(v.w);
}

// flags detect + zero bucket cursors / overflow counters (1 block).
__global__ __launch_bounds__(256) void k_detect(const unsigned* __restrict__ xw,
                                                const int* __restrict__ eiw,
                                                int E, int* __restrict__ flags,
                                                int* __restrict__ gcur) {
    for (int i = threadIdx.x; i < 514; i += 256) gcur[i] = 0;  // gcur[512]+ovfAcnt+ovf2cnt
    __shared__ int s_bf16like, s_oddnz;
    if (threadIdx.x == 0) { s_bf16like = 0; s_oddnz = 0; }
    __syncthreads();
    int c = 0;
    for (int i = threadIdx.x; i < 4096; i += 256) {
        unsigned ex = ((xw[i] & 0xffffu) >> 7) & 0xffu;
        if (ex >= 117u && ex <= 130u) c++;
    }
    atomicAdd(&s_bf16like, c);
    int nz = 0;
    for (int i = threadIdx.x; i < 2048; i += 256)
        if (eiw[2 * i + 1] != 0) nz++;
    atomicAdd(&s_oddnz, nz);
    __syncthreads();
    if (threadIdx.x == 0) {
        flags[0] = (s_bf16like < 2048) ? 1 : 0;
        flags[1] = (s_oddnz == 0) ? 1 : 0;
    }
}

// Phase A: partition edges into destination buckets; edges stashed in registers
// between the histogram and scatter passes (single edge-list read). 2048/block.
__global__ __launch_bounds__(256) void k_binA(const int* __restrict__ ei, int E, int N,
                                              int nbuk,
                                              int* __restrict__ gcur,
                                              int2* __restrict__ pairs,
                                              int2* __restrict__ ovfA,
                                              int* __restrict__ ovfAcnt,
                                              const int* __restrict__ flags) {
    __shared__ int hist[512];
    __shared__ int gbase[512];
    const int tid = threadIdx.x;
    const long base = (long)blockIdx.x * 2048;
    const bool i64 = flags[1] != 0;
    int se[8], de[8];
    for (int b = tid; b < nbuk; b += 256) hist[b] = 0;
    __syncthreads();
    // pass 1: load + validate + histogram
#pragma unroll
    for (int j = 0; j < 8; ++j) {
        long i = base + j * 256 + tid;
        int s = 0, d = -1;
        if (i < E) {
            if (i64) { s = ((const int2*)ei)[i].x; d = ((const int2*)(ei + 2 * (long)E))[i].x; }
            else     { s = ei[i]; d = ei[(long)E + i]; }
            if ((unsigned)s >= (unsigned)N || (unsigned)d >= (unsigned)N) d = -1;
        }
        se[j] = s; de[j] = d;
        if (d >= 0) atomicAdd(&hist[d / NPB], 1);
    }
    __syncthreads();
    // reserve contiguous slices; reuse hist as relative cursor
    for (int b = tid; b < nbuk; b += 256) {
        int h = hist[b];
        gbase[b] = h > 0 ? atomicAdd(&gcur[b], h) : 0;
        hist[b] = 0;
    }
    __syncthreads();
    // pass 2: scatter pairs from registers into reserved slices
#pragma unroll
    for (int j = 0; j < 8; ++j) {
        int d = de[j];
        if (d < 0) continue;
        int b = d / NPB;
        int p = gbase[b] + atomicAdd(&hist[b], 1);
        if (p < BCAP) {
            pairs[(long)b * BCAP + p] = make_int2(d, se[j]);
        } else {
            int op = atomicAdd(ovfAcnt, 1);
            if (op < OVF_MAX) ovfA[op] = make_int2(d, se[j]);
        }
    }
}

// Phase B: per bucket, build cnt+slots in LDS, dense writeout.
__global__ __launch_bounds__(256) void k_binB(const int* __restrict__ gcur,
                                              const int2* __restrict__ pairs,
                                              int* __restrict__ cnt,
                                              int* __restrict__ slots,
                                              int2* __restrict__ ovf2,
                                              int* __restrict__ ovf2cnt, int N) {
    __shared__ int cntL[NPB];
    __shared__ __align__(16) int slotsL[NPB * CAP];
    const int b = blockIdx.x;
    const int tid = threadIdx.x;
    const int d0 = b * NPB;
    const int nd = min(NPB, N - d0);
    if (nd <= 0) return;
    for (int i = tid; i < NPB; i += 256) cntL[i] = 0;
    __syncthreads();
    const int c = min(gcur[b], BCAP);
    const int2* pb = pairs + (long)b * BCAP;
    for (int i = tid; i < c; i += 256) {
        int2 p = pb[i];
        int ld = p.x - d0;
        int pos = atomicAdd(&cntL[ld], 1);
        if (pos < CAP) {
            slotsL[ld * CAP + pos] = p.y;
        } else {
            int op = atomicAdd(ovf2cnt, 1);
            if (op < OVF_MAX) ovf2[op] = p;
        }
    }
    __syncthreads();
    for (int i = tid; i < nd; i += 256) cnt[d0 + i] = cntL[i];
    const uint4* sv = (const uint4*)slotsL;
    uint4* gv = (uint4*)(slots + (long)d0 * CAP);
    const int total4 = (nd * CAP) >> 2;
    for (int i = tid; i < total4; i += 256) gv[i] = sv[i];
}

// Patch: fold phase-A overflow edges into cnt/slots (empty in normal runs).
__global__ __launch_bounds__(256) void k_patch(const int2* __restrict__ ovfA,
                                               const int* __restrict__ ovfAcnt,
                                               int* __restrict__ cnt,
                                               int* __restrict__ slots,
                                               int2* __restrict__ ovf2,
                                               int* __restrict__ ovf2cnt, int N) {
    int n = *ovfAcnt; n = n < OVF_MAX ? n : OVF_MAX;
    for (int i = blockIdx.x * 256 + threadIdx.x; i < n; i += gridDim.x * 256) {
        int2 p = ovfA[i];
        int pos = atomicAdd(&cnt[p.x], 1);
        if (pos < CAP) {
            slots[(long)p.x * CAP + pos] = p.y;
        } else {
            int op = atomicAdd(ovf2cnt, 1);
            if (op < OVF_MAX) ovf2[op] = p;
        }
    }
}

// MFMA GEMM: G[row,:C] = bf16( rsqrt(cnt[row]+1) * (X[row,:128] @ W[:128,:C]) )
template<int CT>
__global__ __launch_bounds__(256) void k_gemm(const void* __restrict__ Xp, int x_follows_flag,
                                              const void* __restrict__ Wp,
                                              const int* __restrict__ cnt,
                                              __hip_bfloat16* __restrict__ G,
                                              const int* __restrict__ flags, int N) {
    constexpr int C = CT * 16;
    __shared__ __align__(16) short Wt[C * 136];   // W^T bf16, pad 128->136
    const bool f32m = flags[0] != 0;
    const bool xf32 = (x_follows_flag != 0) && f32m;
    const int tid = threadIdx.x;
    for (int i = tid; i < 128 * C; i += 256) {
        int k = i / C, n = i % C;
        float wv = f32m ? ((const float*)Wp)[(long)k * C + n]
                        : bf2f(((const __hip_bfloat16*)Wp)[(long)k * C + n]);
        Wt[n * 136 + k] = (short)f2bfu(wv);
    }
    __syncthreads();
    const int w = tid >> 6, lane = tid & 63;
    const int m = lane & 15, quad = lane >> 4;
    const int rowA = blockIdx.x * 64 + w * 16 + m;
    const int rowc = rowA < N ? rowA : N - 1;
    s16x8 afr[4];
#pragma unroll
    for (int kc = 0; kc < 4; ++kc) {
        const int k0 = kc * 32 + quad * 8;
        if (!xf32) {
            afr[kc] = *(const s16x8*)((const __hip_bfloat16*)Xp + (long)rowc * 128 + k0);
        } else {
            const float* p = (const float*)Xp + (long)rowc * 128 + k0;
            s16x8 t;
#pragma unroll
            for (int j = 0; j < 8; ++j) t[j] = (short)f2bfu(p[j]);
            afr[kc] = t;
        }
    }
    const int rbase = blockIdx.x * 64 + w * 16 + quad * 4;
    float dv[4];
#pragma unroll
    for (int r = 0; r < 4; ++r) {
        int rr = min(rbase + r, N - 1);
        dv[r] = rsqrtf((float)(cnt[rr] + 1));
    }
#pragma unroll
    for (int ct = 0; ct < CT; ++ct) {
        f32x4 acc = {0.f, 0.f, 0.f, 0.f};
#pragma unroll
        for (int kc = 0; kc < 4; ++kc) {
            s16x8 bfr = *(const s16x8*)&Wt[(ct * 16 + m) * 136 + kc * 32 + quad * 8];
            acc = __builtin_amdgcn_mfma_f32_16x16x32_bf16(afr[kc], bfr, acc, 0, 0, 0);
        }
#pragma unroll
        for (int r = 0; r < 4; ++r) {
            int rr = rbase + r;
            if (rr < N) G[(long)rr * C + ct * 16 + m] = __float2bfloat16(dv[r] * acc[r]);
        }
    }
}

// XCD-column-split gather. F total cols, TILES tiles of 32 cols. Each node group
// is 4 lanes (8 cols / 16B per lane). tile chosen from blockIdx%8 so each XCD
// (assuming round-robin blockIdx->XCD) touches only a 3.2MB slice of G -> L2-hit.
// OUT[d, tile cols] = act( rsqrt(cnt[d]+1) * (G[d,t] + sum_s G[s,t]) + bias )
template<int F, int TILES, int LAYER1>
__global__ __launch_bounds__(256) void k_gather(const __hip_bfloat16* __restrict__ G,
                                                const int* __restrict__ cnt,
                                                const int* __restrict__ slots,
                                                const int2* __restrict__ ovf2,
                                                const int* __restrict__ ovf2cnt,
                                                const void* __restrict__ bias,
                                                void* __restrict__ outp,
                                                const int* __restrict__ flags, int N) {
    constexpr int SUBS = 8 / TILES;          // node sub-chunks per 8-block group
    const int h = blockIdx.x & 7;
    const int nc = blockIdx.x >> 3;
    const int tile = h / SUBS;               // 0..TILES-1, constant per XCD
    const int sub = h % SUBS;
    const int tid = threadIdx.x;
    const int grp = tid >> 2, lane = tid & 3;    // 64 nodes/block, 4 lanes/node
    const int node = nc * (64 * SUBS) + sub * 64 + grp;
    if (node >= N) return;
    const int cd = cnt[node];
    const float wself = rsqrtf((float)(cd + 1));
    const int m = cd < CAP ? cd : CAP;
    const int* sl = slots + (long)node * CAP;
    const __hip_bfloat16* Gt = G + tile * 32;    // column-slice base
    float acc[8] = {0, 0, 0, 0, 0, 0, 0, 0};
    acc_add(acc, ((const uint4*)(Gt + (long)node * F))[lane]);   // self loop
    int i = 0;
    for (; i + 3 < m; i += 4) {
        int s0 = sl[i], s1 = sl[i + 1], s2 = sl[i + 2], s3 = sl[i + 3];
        uint4 v0 = ((const uint4*)(Gt + (long)s0 * F))[lane];
        uint4 v1 = ((const uint4*)(Gt + (long)s1 * F))[lane];
        uint4 v2 = ((const uint4*)(Gt + (long)s2 * F))[lane];
        uint4 v3 = ((const uint4*)(Gt + (long)s3 * F))[lane];
        acc_add(acc, v0); acc_add(acc, v1); acc_add(acc, v2); acc_add(acc, v3);
    }
    for (; i < m; ++i)
        acc_add(acc, ((const uint4*)(Gt + (long)sl[i] * F))[lane]);
    if (cd > CAP) {  // rare overflow
        int oc = *ovf2cnt; oc = oc < OVF_MAX ? oc : OVF_MAX;
        for (int j = 0; j < oc; ++j)
            if (ovf2[j].x == node)
                acc_add(acc, ((const uint4*)(Gt + (long)ovf2[j].y * F))[lane]);
    }
    const bool f32m = flags[0] != 0;
    const int c0 = tile * 32 + lane * 8;
    float bv[8];
    if (f32m) {
        const float4* bp = (const float4*)((const float*)bias + c0);
        float4 b0 = bp[0], b1 = bp[1];
        bv[0] = b0.x; bv[1] = b0.y; bv[2] = b0.z; bv[3] = b0.w;
        bv[4] = b1.x; bv[5] = b1.y; bv[6] = b1.z; bv[7] = b1.w;
    } else {
        uint4 b = *(const uint4*)((const __hip_bfloat16*)bias + c0);
        bv[0] = lo2f(b.x); bv[1] = hi2f(b.x); bv[2] = lo2f(b.y); bv[3] = hi2f(b.y);
        bv[4] = lo2f(b.z); bv[5] = hi2f(b.z); bv[6] = lo2f(b.w); bv[7] = hi2f(b.w);
    }
    float o[8];
#pragma unroll
    for (int c = 0; c < 8; ++c) {
        float v = wself * acc[c] + bv[c];
        o[c] = (LAYER1 && v < 0.f) ? 0.f : v;
    }
    if (LAYER1 || !f32m) {
        uint4 pv = { pack2(o[0], o[1]), pack2(o[2], o[3]), pack2(o[4], o[5]), pack2(o[6], o[7]) };
        ((uint4*)outp)[(long)node * (F / 8) + tile * 4 + lane] = pv;
    } else {
        float4* op = (float4*)((float*)outp + (long)node * F + c0);
        op[0] = make_float4(o[0], o[1], o[2], o[3]);
        op[1] = make_float4(o[4], o[5], o[6], o[7]);
    }
}

extern "C" void kernel_launch(void* const* d_in, const int* in_sizes, int n_in,
                              void* d_out, int out_size, void* d_ws, size_t ws_size,
                              hipStream_t stream) {
    const void* x  = d_in[0];
    const int*  ei = (const int*)d_in[1];
    const void* W1 = d_in[2];
    const void* b1 = d_in[3];
    const void* W2 = d_in[4];
    const void* b2 = d_in[5];

    const int N = in_sizes[0] / FIN;   // 50000
    const int E = in_sizes[1] / 2;     // 800000
    const int nbuk = (N + NPB - 1) / NPB;   // 511 (<=512 supported)

    // ws layout (bytes), peak ~37.1MB (ws_size ~268MB):
    //   flags @0
    //   gcur  @4096   (512 ints; [512]=ovfAcnt, [513]=ovf2cnt)
    //   cnt   @65536  (4N)
    //   ovfA  @524288  (512KB int2)
    //   ovf2  @1048576 (512KB int2)
    //   slots @2097152 (N*CAP*4 = 9.6MB)
    //   g     @11730944 (12.8MB bf16; g2 overlays)
    //   pairs @24530944 (nbuk*BCAP*8 = 12.56MB; h1 overlays after binB/patch)
    char* ws = (char*)d_ws;
    int*   flags   = (int*)ws;
    int*   gcur    = (int*)(ws + 4096);
    int*   ovfAcnt = gcur + 512;
    int*   ovf2cnt = gcur + 513;
    int*   cnt     = (int*)(ws + 65536);
    int2*  ovfA    = (int2*)(ws + 524288);
    int2*  ovf2    = (int2*)(ws + 1048576);
    int*   slots   = (int*)(ws + 2097152);
    __hip_bfloat16* g  = (__hip_bfloat16*)(ws + 11730944);
    __hip_bfloat16* g2 = g;                                     // overlays g
    int2*  pairs   = (int2*)(ws + 24530944);
    __hip_bfloat16* h1 = (__hip_bfloat16*)(ws + 24530944);      // overlays pairs

    const int GB = (N + 63) / 64;
    const int AB = (E + 2047) / 2048;

    k_detect<<<1, 256, 0, stream>>>((const unsigned*)x, ei, E, flags, gcur);
    k_binA<<<AB, 256, 0, stream>>>(ei, E, N, nbuk, gcur, pairs, ovfA, ovfAcnt, flags);
    k_binB<<<nbuk, 256, 0, stream>>>(gcur, pairs, cnt, slots, ovf2, ovf2cnt, N);
    k_patch<<<32, 256, 0, stream>>>(ovfA, ovfAcnt, cnt, slots, ovf2, ovf2cnt, N);
    // layer 1
    k_gemm<8><<<GB, 256, 0, stream>>>(x, 1, W1, cnt, g, flags, N);
    // F=128: 4 tiles x 2 sub-chunks -> 8 blocks per 128 nodes
    k_gather<128, 4, 1><<<((N + 127) / 128) * 8, 256, 0, stream>>>(g, cnt, slots, ovf2, ovf2cnt, b1, h1, flags, N);
    // layer 2
    k_gemm<4><<<GB, 256, 0, stream>>>(h1, 0, W2, cnt, g2, flags, N);
    // F=64: 2 tiles x 4 sub-chunks -> 8 blocks per 256 nodes
    k_gather<64, 2, 0><<<((N + 255) / 256) * 8, 256, 0, stream>>>(g2, cnt, slots, ovf2, ovf2cnt, b2, d_out, flags, N);
}

// Round 11
// 208.682 us; speedup vs baseline: 1.1210x; 1.1210x over previous
//
#include <hip/hip_runtime.h>
#include <hip/hip_bf16.h>

// GCN 2-layer encoder. R11: revert R10 column-split (sub-line reads amplified
// fetch 2x). Full-row gathers (R9 geometry) + u16 node indices (halve slot &
// build traffic; N<=65536 path, int fallback) + 8-deep gather ILP.
// out[d] = dinv[d] * sum_{s in N(d) U {d}} g[s] + b,  g[s] = dinv[s]*(in@W)[s]

constexpr int FIN = 128;
constexpr int HID = 128;
constexpr int FOUT = 64;
constexpr int CAP = 48;     // adjacency slots per node
constexpr int NPB = 98;     // nodes per bucket
constexpr int BCAP = 3072;  // pairs per bucket region
constexpr int OVF_MAX = 65536;

typedef __attribute__((ext_vector_type(8))) short s16x8;
typedef __attribute__((ext_vector_type(4))) float f32x4;

static __device__ __forceinline__ float bf2f(__hip_bfloat16 v) { return __bfloat162float(v); }
static __device__ __forceinline__ float lo2f(unsigned u) { union { unsigned i; float f; } c; c.i = u << 16; return c.f; }
static __device__ __forceinline__ float hi2f(unsigned u) { union { unsigned i; float f; } c; c.i = u & 0xffff0000u; return c.f; }
static __device__ __forceinline__ unsigned short f2bfu(float f) {
    __hip_bfloat16 h = __float2bfloat16(f);
    union { __hip_bfloat16 h; unsigned short u; } c; c.h = h; return c.u;
}
static __device__ __forceinline__ unsigned pack2(float a, float b) {
    return (unsigned)f2bfu(a) | ((unsigned)f2bfu(b) << 16);
}
static __device__ __forceinline__ void acc_add(float* acc, uint4 v) {
    acc[0] += lo2f(v.x); acc[1] += hi2f(v.x);
    acc[2] += lo2f(v.y); acc[3] += hi2f(v.y);
    acc[4] += lo2f(v.z); acc[5] += hi2f(v.z);
    acc[6] += lo2f(v.w); acc[7] += hi2f(v.w);
}

// flags detect (block 0) + zero gcur/ovf counters + zero cnt (all blocks).
__global__ __launch_bounds__(256) void k_detect(const unsigned* __restrict__ xw,
                                                const int* __restrict__ eiw,
                                                int E, int* __restrict__ flags,
                                                int* __restrict__ gcur,
                                                int* __restrict__ cnt, int N) {
    for (long i = (long)blockIdx.x * 256 + threadIdx.x; i < N; i += (long)gridDim.x * 256)
        cnt[i] = 0;
    if (blockIdx.x != 0) return;
    for (int i = threadIdx.x; i < 514; i += 256) gcur[i] = 0;  // gcur[512]+ovfAcnt+ovf2cnt
    __shared__ int s_bf16like, s_oddnz;
    if (threadIdx.x == 0) { s_bf16like = 0; s_oddnz = 0; }
    __syncthreads();
    int c = 0;
    for (int i = threadIdx.x; i < 4096; i += 256) {
        unsigned ex = ((xw[i] & 0xffffu) >> 7) & 0xffu;
        if (ex >= 117u && ex <= 130u) c++;
    }
    atomicAdd(&s_bf16like, c);
    int nz = 0;
    for (int i = threadIdx.x; i < 2048; i += 256)
        if (eiw[2 * i + 1] != 0) nz++;
    atomicAdd(&s_oddnz, nz);
    __syncthreads();
    if (threadIdx.x == 0) {
        flags[0] = (s_bf16like < 2048) ? 1 : 0;
        flags[1] = (s_oddnz == 0) ? 1 : 0;
    }
}

// Phase A (u16 path): partition edges into buckets; packed u32 pairs
// ((d-d0)<<16 | s). Register-stashed single edge-list read. 2048 edges/block.
__global__ __launch_bounds__(256) void k_binA(const int* __restrict__ ei, int E, int N,
                                              int nbuk,
                                              int* __restrict__ gcur,
                                              unsigned* __restrict__ pairs,
                                              int2* __restrict__ ovfA,
                                              int* __restrict__ ovfAcnt,
                                              const int* __restrict__ flags) {
    __shared__ int hist[512];
    __shared__ int gbase[512];
    const int tid = threadIdx.x;
    const long base = (long)blockIdx.x * 2048;
    const bool i64 = flags[1] != 0;
    int se[8], de[8];
    for (int b = tid; b < nbuk; b += 256) hist[b] = 0;
    __syncthreads();
#pragma unroll
    for (int j = 0; j < 8; ++j) {
        long i = base + j * 256 + tid;
        int s = 0, d = -1;
        if (i < E) {
            if (i64) { s = ((const int2*)ei)[i].x; d = ((const int2*)(ei + 2 * (long)E))[i].x; }
            else     { s = ei[i]; d = ei[(long)E + i]; }
            if ((unsigned)s >= (unsigned)N || (unsigned)d >= (unsigned)N) d = -1;
        }
        se[j] = s; de[j] = d;
        if (d >= 0) atomicAdd(&hist[d / NPB], 1);
    }
    __syncthreads();
    for (int b = tid; b < nbuk; b += 256) {
        int h = hist[b];
        gbase[b] = h > 0 ? atomicAdd(&gcur[b], h) : 0;
        hist[b] = 0;
    }
    __syncthreads();
#pragma unroll
    for (int j = 0; j < 8; ++j) {
        int d = de[j];
        if (d < 0) continue;
        int b = d / NPB;
        int p = gbase[b] + atomicAdd(&hist[b], 1);
        if (p < BCAP) {
            pairs[(long)b * BCAP + p] = ((unsigned)(d - b * NPB) << 16) | (unsigned)se[j];
        } else {
            int op = atomicAdd(ovfAcnt, 1);
            if (op < OVF_MAX) ovfA[op] = make_int2(d, se[j]);
        }
    }
}

// Phase B (u16): per bucket, build cnt+slots in LDS, dense vector writeout.
__global__ __launch_bounds__(256) void k_binB(const int* __restrict__ gcur,
                                              const unsigned* __restrict__ pairs,
                                              int* __restrict__ cnt,
                                              unsigned short* __restrict__ slots,
                                              int2* __restrict__ ovf2,
                                              int* __restrict__ ovf2cnt, int N) {
    __shared__ int cntL[NPB];
    __shared__ __align__(16) unsigned short slotsL[NPB * CAP];
    const int b = blockIdx.x;
    const int tid = threadIdx.x;
    const int d0 = b * NPB;
    const int nd = min(NPB, N - d0);
    if (nd <= 0) return;
    for (int i = tid; i < NPB; i += 256) cntL[i] = 0;
    __syncthreads();
    const int c = min(gcur[b], BCAP);
    const unsigned* pb = pairs + (long)b * BCAP;
    for (int i = tid; i < c; i += 256) {
        unsigned p = pb[i];
        int ld = p >> 16;
        int pos = atomicAdd(&cntL[ld], 1);
        if (pos < CAP) {
            slotsL[ld * CAP + pos] = (unsigned short)(p & 0xffffu);
        } else {
            int op = atomicAdd(ovf2cnt, 1);
            if (op < OVF_MAX) ovf2[op] = make_int2(d0 + ld, (int)(p & 0xffffu));
        }
    }
    __syncthreads();
    for (int i = tid; i < nd; i += 256) cnt[d0 + i] = cntL[i];
    const uint4* sv = (const uint4*)slotsL;
    uint4* gv = (uint4*)(slots + (long)d0 * CAP);   // d0*CAP*2 = b*9408, 16B-aligned
    const int total8 = (nd * CAP) >> 3;             // CAP=48 divisible by 8
    for (int i = tid; i < total8; i += 256) gv[i] = sv[i];
}

// Patch: fold phase-A overflow edges into cnt/slots (empty in normal runs).
template<typename ST>
__global__ __launch_bounds__(256) void k_patch(const int2* __restrict__ ovfA,
                                               const int* __restrict__ ovfAcnt,
                                               int* __restrict__ cnt,
                                               ST* __restrict__ slots,
                                               int2* __restrict__ ovf2,
                                               int* __restrict__ ovf2cnt, int N) {
    int n = *ovfAcnt; n = n < OVF_MAX ? n : OVF_MAX;
    for (int i = blockIdx.x * 256 + threadIdx.x; i < n; i += gridDim.x * 256) {
        int2 p = ovfA[i];
        int pos = atomicAdd(&cnt[p.x], 1);
        if (pos < CAP) {
            slots[(long)p.x * CAP + pos] = (ST)p.y;
        } else {
            int op = atomicAdd(ovf2cnt, 1);
            if (op < OVF_MAX) ovf2[op] = p;
        }
    }
}

// Fallback direct build for N > 65536 (int slots).
__global__ __launch_bounds__(256) void k_build_direct(const int* __restrict__ ei, int E, int N,
                                                      int* __restrict__ cnt,
                                                      int* __restrict__ slots,
                                                      int2* __restrict__ ovf2,
                                                      int* __restrict__ ovf2cnt,
                                                      const int* __restrict__ flags) {
    long i = (long)blockIdx.x * 256 + threadIdx.x;
    if (i >= E) return;
    int s, d;
    if (flags[1]) { s = ((const int2*)ei)[i].x; d = ((const int2*)(ei + 2 * (long)E))[i].x; }
    else          { s = ei[i]; d = ei[(long)E + i]; }
    if ((unsigned)s >= (unsigned)N || (unsigned)d >= (unsigned)N) return;
    int pos = atomicAdd(&cnt[d], 1);
    if (pos < CAP) {
        slots[(long)d * CAP + pos] = s;
    } else {
        int op = atomicAdd(ovf2cnt, 1);
        if (op < OVF_MAX) ovf2[op] = make_int2(d, s);
    }
}

// MFMA GEMM: G[row,:C] = bf16( rsqrt(cnt[row]+1) * (X[row,:128] @ W[:128,:C]) )
template<int CT>
__global__ __launch_bounds__(256) void k_gemm(const void* __restrict__ Xp, int x_follows_flag,
                                              const void* __restrict__ Wp,
                                              const int* __restrict__ cnt,
                                              __hip_bfloat16* __restrict__ G,
                                              const int* __restrict__ flags, int N) {
    constexpr int C = CT * 16;
    __shared__ __align__(16) short Wt[C * 136];   // W^T bf16, pad 128->136
    const bool f32m = flags[0] != 0;
    const bool xf32 = (x_follows_flag != 0) && f32m;
    const int tid = threadIdx.x;
    for (int i = tid; i < 128 * C; i += 256) {
        int k = i / C, n = i % C;
        float wv = f32m ? ((const float*)Wp)[(long)k * C + n]
                        : bf2f(((const __hip_bfloat16*)Wp)[(long)k * C + n]);
        Wt[n * 136 + k] = (short)f2bfu(wv);
    }
    __syncthreads();
    const int w = tid >> 6, lane = tid & 63;
    const int m = lane & 15, quad = lane >> 4;
    const int rowA = blockIdx.x * 64 + w * 16 + m;
    const int rowc = rowA < N ? rowA : N - 1;
    s16x8 afr[4];
#pragma unroll
    for (int kc = 0; kc < 4; ++kc) {
        const int k0 = kc * 32 + quad * 8;
        if (!xf32) {
            afr[kc] = *(const s16x8*)((const __hip_bfloat16*)Xp + (long)rowc * 128 + k0);
        } else {
            const float* p = (const float*)Xp + (long)rowc * 128 + k0;
            s16x8 t;
#pragma unroll
            for (int j = 0; j < 8; ++j) t[j] = (short)f2bfu(p[j]);
            afr[kc] = t;
        }
    }
    const int rbase = blockIdx.x * 64 + w * 16 + quad * 4;
    float dv[4];
#pragma unroll
    for (int r = 0; r < 4; ++r) {
        int rr = min(rbase + r, N - 1);
        dv[r] = rsqrtf((float)(cnt[rr] + 1));
    }
#pragma unroll
    for (int ct = 0; ct < CT; ++ct) {
        f32x4 acc = {0.f, 0.f, 0.f, 0.f};
#pragma unroll
        for (int kc = 0; kc < 4; ++kc) {
            s16x8 bfr = *(const s16x8*)&Wt[(ct * 16 + m) * 136 + kc * 32 + quad * 8];
            acc = __builtin_amdgcn_mfma_f32_16x16x32_bf16(afr[kc], bfr, acc, 0, 0, 0);
        }
#pragma unroll
        for (int r = 0; r < 4; ++r) {
            int rr = rbase + r;
            if (rr < N) G[(long)rr * C + ct * 16 + m] = __float2bfloat16(dv[r] * acc[r]);
        }
    }
}

// LDS-free full-row gather, 8-deep ILP.
// OUT[d,:F] = act( rsqrt(cnt[d]+1) * (G[d,:] + sum_s G[s,:]) + bias )
template<int F, int LAYER1, typename ST>
__global__ __launch_bounds__(256) void k_gather(const __hip_bfloat16* __restrict__ G,
                                                const int* __restrict__ cnt,
                                                const ST* __restrict__ slots,
                                                const int2* __restrict__ ovf2,
                                                const int* __restrict__ ovf2cnt,
                                                const void* __restrict__ bias,
                                                void* __restrict__ outp,
                                                const int* __restrict__ flags, int N) {
    constexpr int L = F / 8;
    constexpr int NODES = 256 / L;
    const int tid = threadIdx.x;
    const int grp = tid / L, lane = tid % L;
    const int node = blockIdx.x * NODES + grp;
    if (node >= N) return;
    const int cd = cnt[node];
    const float wself = rsqrtf((float)(cd + 1));
    const int m = cd < CAP ? cd : CAP;
    const ST* sl = slots + (long)node * CAP;
    float acc[8] = {0, 0, 0, 0, 0, 0, 0, 0};
    acc_add(acc, ((const uint4*)(G + (long)node * F))[lane]);   // self loop
    int i = 0;
    for (; i + 7 < m; i += 8) {
        int s0 = sl[i], s1 = sl[i + 1], s2 = sl[i + 2], s3 = sl[i + 3];
        int s4 = sl[i + 4], s5 = sl[i + 5], s6 = sl[i + 6], s7 = sl[i + 7];
        uint4 v0 = ((const uint4*)(G + (long)s0 * F))[lane];
        uint4 v1 = ((const uint4*)(G + (long)s1 * F))[lane];
        uint4 v2 = ((const uint4*)(G + (long)s2 * F))[lane];
        uint4 v3 = ((const uint4*)(G + (long)s3 * F))[lane];
        uint4 v4 = ((const uint4*)(G + (long)s4 * F))[lane];
        uint4 v5 = ((const uint4*)(G + (long)s5 * F))[lane];
        uint4 v6 = ((const uint4*)(G + (long)s6 * F))[lane];
        uint4 v7 = ((const uint4*)(G + (long)s7 * F))[lane];
        acc_add(acc, v0); acc_add(acc, v1); acc_add(acc, v2); acc_add(acc, v3);
        acc_add(acc, v4); acc_add(acc, v5); acc_add(acc, v6); acc_add(acc, v7);
    }
    for (; i + 3 < m; i += 4) {
        int s0 = sl[i], s1 = sl[i + 1], s2 = sl[i + 2], s3 = sl[i + 3];
        uint4 v0 = ((const uint4*)(G + (long)s0 * F))[lane];
        uint4 v1 = ((const uint4*)(G + (long)s1 * F))[lane];
        uint4 v2 = ((const uint4*)(G + (long)s2 * F))[lane];
        uint4 v3 = ((const uint4*)(G + (long)s3 * F))[lane];
        acc_add(acc, v0); acc_add(acc, v1); acc_add(acc, v2); acc_add(acc, v3);
    }
    for (; i < m; ++i)
        acc_add(acc, ((const uint4*)(G + (long)sl[i] * F))[lane]);
    if (cd > CAP) {  // rare overflow
        int oc = *ovf2cnt; oc = oc < OVF_MAX ? oc : OVF_MAX;
        for (int j = 0; j < oc; ++j)
            if (ovf2[j].x == node)
                acc_add(acc, ((const uint4*)(G + (long)ovf2[j].y * F))[lane]);
    }
    const bool f32m = flags[0] != 0;
    const int c0 = lane * 8;
    float bv[8];
    if (f32m) {
        const float4* bp = (const float4*)((const float*)bias + c0);
        float4 b0 = bp[0], b1 = bp[1];
        bv[0] = b0.x; bv[1] = b0.y; bv[2] = b0.z; bv[3] = b0.w;
        bv[4] = b1.x; bv[5] = b1.y; bv[6] = b1.z; bv[7] = b1.w;
    } else {
        uint4 b = *(const uint4*)((const __hip_bfloat16*)bias + c0);
        bv[0] = lo2f(b.x); bv[1] = hi2f(b.x); bv[2] = lo2f(b.y); bv[3] = hi2f(b.y);
        bv[4] = lo2f(b.z); bv[5] = hi2f(b.z); bv[6] = lo2f(b.w); bv[7] = hi2f(b.w);
    }
    float o[8];
#pragma unroll
    for (int c = 0; c < 8; ++c) {
        float v = wself * acc[c] + bv[c];
        o[c] = (LAYER1 && v < 0.f) ? 0.f : v;
    }
    if (LAYER1 || !f32m) {
        uint4 pv = { pack2(o[0], o[1]), pack2(o[2], o[3]), pack2(o[4], o[5]), pack2(o[6], o[7]) };
        ((uint4*)outp)[(long)node * L + lane] = pv;
    } else {
        float4* op = (float4*)((float*)outp + (long)node * F + c0);
        op[0] = make_float4(o[0], o[1], o[2], o[3]);
        op[1] = make_float4(o[4], o[5], o[6], o[7]);
    }
}

extern "C" void kernel_launch(void* const* d_in, const int* in_sizes, int n_in,
                              void* d_out, int out_size, void* d_ws, size_t ws_size,
                              hipStream_t stream) {
    const void* x  = d_in[0];
    const int*  ei = (const int*)d_in[1];
    const void* W1 = d_in[2];
    const void* b1 = d_in[3];
    const void* W2 = d_in[4];
    const void* b2 = d_in[5];

    const int N = in_sizes[0] / FIN;   // 50000
    const int E = in_sizes[1] / 2;     // 800000
    const int nbuk = (N + NPB - 1) / NPB;   // 511 (<=512 supported for u16 path)

    // ws layout (bytes), peak ~37.3MB (ws_size ~268MB):
    //   flags @0
    //   gcur  @4096   (512 ints; [512]=ovfAcnt, [513]=ovf2cnt)
    //   cnt   @65536  (4N)
    //   ovfA  @524288  (512KB int2)
    //   ovf2  @1048576 (512KB int2)
    //   slots @2097152 (u16: N*CAP*2=4.8MB; int fallback: 9.6MB; region is 9.6MB)
    //   g     @11730944 (12.8MB bf16; g2 overlays)
    //   pairs @24530944 (u32: nbuk*BCAP*4 = 6.28MB; h1 overlays after binB/patch)
    char* ws = (char*)d_ws;
    int*   flags   = (int*)ws;
    int*   gcur    = (int*)(ws + 4096);
    int*   ovfAcnt = gcur + 512;
    int*   ovf2cnt = gcur + 513;
    int*   cnt     = (int*)(ws + 65536);
    int2*  ovfA    = (int2*)(ws + 524288);
    int2*  ovf2    = (int2*)(ws + 1048576);
    unsigned short* slots16 = (unsigned short*)(ws + 2097152);
    int*   slots32 = (int*)(ws + 2097152);
    __hip_bfloat16* g  = (__hip_bfloat16*)(ws + 11730944);
    __hip_bfloat16* g2 = g;                                     // overlays g
    unsigned* pairs = (unsigned*)(ws + 24530944);
    __hip_bfloat16* h1 = (__hip_bfloat16*)(ws + 24530944);      // overlays pairs

    const int GB = (N + 63) / 64;
    const int AB = (E + 2047) / 2048;
    const int EB = (E + 255) / 256;

    k_detect<<<64, 256, 0, stream>>>((const unsigned*)x, ei, E, flags, gcur, cnt, N);

    if (N <= 65536 && nbuk <= 512) {
        k_binA<<<AB, 256, 0, stream>>>(ei, E, N, nbuk, gcur, pairs, ovfA, ovfAcnt, flags);
        k_binB<<<nbuk, 256, 0, stream>>>(gcur, pairs, cnt, slots16, ovf2, ovf2cnt, N);
        k_patch<unsigned short><<<32, 256, 0, stream>>>(ovfA, ovfAcnt, cnt, slots16, ovf2, ovf2cnt, N);
        k_gemm<8><<<GB, 256, 0, stream>>>(x, 1, W1, cnt, g, flags, N);
        k_gather<128, 1, unsigned short><<<(N + 15) / 16, 256, 0, stream>>>(
            g, cnt, slots16, ovf2, ovf2cnt, b1, h1, flags, N);
        k_gemm<4><<<GB, 256, 0, stream>>>(h1, 0, W2, cnt, g2, flags, N);
        k_gather<64, 0, unsigned short><<<(N + 31) / 32, 256, 0, stream>>>(
            g2, cnt, slots16, ovf2, ovf2cnt, b2, d_out, flags, N);
    } else {
        k_build_direct<<<EB, 256, 0, stream>>>(ei, E, N, cnt, slots32, ovf2, ovf2cnt, flags);
        k_gemm<8><<<GB, 256, 0, stream>>>(x, 1, W1, cnt, g, flags, N);
        k_gather<128, 1, int><<<(N + 15) / 16, 256, 0, stream>>>(
            g, cnt, slots32, ovf2, ovf2cnt, b1, h1, flags, N);
        k_gemm<4><<<GB, 256, 0, stream>>>(h1, 0, W2, cnt, g2, flags, N);
        k_gather<64, 0, int><<<(N + 31) / 32, 256, 0, stream>>>(
            g2, cnt, slots32, ovf2, ovf2cnt, b2, d_out, flags, N);
    }
}

// Round 12
// 202.709 us; speedup vs baseline: 1.1540x; 1.0295x over previous
//
#include <hip/hip_runtime.h>
#include <hip/hip_bf16.h>

// GCN 2-layer encoder. R12: gather1 split into two column-plane passes
// (g stored as 2 planes of 64 cols = 128B rows -> per-pass working set 6.4MB
// fits XCD L2 better; full-line granularity per R10 lesson). k_patch folded
// into k_binB. u16 slots, 8-deep gather ILP, MFMA GEMMs.
// out[d] = dinv[d] * sum_{s in N(d) U {d}} g[s] + b,  g[s] = dinv[s]*(in@W)[s]

constexpr int FIN = 128;
constexpr int HID = 128;
constexpr int FOUT = 64;
constexpr int CAP = 48;     // adjacency slots per node
constexpr int NPB = 98;     // nodes per bucket
constexpr int BCAP = 3072;  // pairs per bucket region
constexpr int OVF_MAX = 65536;

typedef __attribute__((ext_vector_type(8))) short s16x8;
typedef __attribute__((ext_vector_type(4))) float f32x4;

static __device__ __forceinline__ float bf2f(__hip_bfloat16 v) { return __bfloat162float(v); }
static __device__ __forceinline__ float lo2f(unsigned u) { union { unsigned i; float f; } c; c.i = u << 16; return c.f; }
static __device__ __forceinline__ float hi2f(unsigned u) { union { unsigned i; float f; } c; c.i = u & 0xffff0000u; return c.f; }
static __device__ __forceinline__ unsigned short f2bfu(float f) {
    __hip_bfloat16 h = __float2bfloat16(f);
    union { __hip_bfloat16 h; unsigned short u; } c; c.h = h; return c.u;
}
static __device__ __forceinline__ unsigned pack2(float a, float b) {
    return (unsigned)f2bfu(a) | ((unsigned)f2bfu(b) << 16);
}
static __device__ __forceinline__ void acc_add(float* acc, uint4 v) {
    acc[0] += lo2f(v.x); acc[1] += hi2f(v.x);
    acc[2] += lo2f(v.y); acc[3] += hi2f(v.y);
    acc[4] += lo2f(v.z); acc[5] += hi2f(v.z);
    acc[6] += lo2f(v.w); acc[7] += hi2f(v.w);
}

// flags detect (block 0) + zero gcur/ovf counters + zero cnt (all blocks).
__global__ __launch_bounds__(256) void k_detect(const unsigned* __restrict__ xw,
                                                const int* __restrict__ eiw,
                                                int E, int* __restrict__ flags,
                                                int* __restrict__ gcur,
                                                int* __restrict__ cnt, int N) {
    for (long i = (long)blockIdx.x * 256 + threadIdx.x; i < N; i += (long)gridDim.x * 256)
        cnt[i] = 0;
    if (blockIdx.x != 0) return;
    for (int i = threadIdx.x; i < 514; i += 256) gcur[i] = 0;  // gcur[512]+ovfAcnt+ovf2cnt
    __shared__ int s_bf16like, s_oddnz;
    if (threadIdx.x == 0) { s_bf16like = 0; s_oddnz = 0; }
    __syncthreads();
    int c = 0;
    for (int i = threadIdx.x; i < 4096; i += 256) {
        unsigned ex = ((xw[i] & 0xffffu) >> 7) & 0xffu;
        if (ex >= 117u && ex <= 130u) c++;
    }
    atomicAdd(&s_bf16like, c);
    int nz = 0;
    for (int i = threadIdx.x; i < 2048; i += 256)
        if (eiw[2 * i + 1] != 0) nz++;
    atomicAdd(&s_oddnz, nz);
    __syncthreads();
    if (threadIdx.x == 0) {
        flags[0] = (s_bf16like < 2048) ? 1 : 0;
        flags[1] = (s_oddnz == 0) ? 1 : 0;
    }
}

// Phase A (u16 path): partition edges into buckets; packed u32 pairs
// ((d-d0)<<16 | s). Register-stashed single edge-list read. 2048 edges/block.
__global__ __launch_bounds__(256) void k_binA(const int* __restrict__ ei, int E, int N,
                                              int nbuk,
                                              int* __restrict__ gcur,
                                              unsigned* __restrict__ pairs,
                                              int2* __restrict__ ovfA,
                                              int* __restrict__ ovfAcnt,
                                              const int* __restrict__ flags) {
    __shared__ int hist[512];
    __shared__ int gbase[512];
    const int tid = threadIdx.x;
    const long base = (long)blockIdx.x * 2048;
    const bool i64 = flags[1] != 0;
    int se[8], de[8];
    for (int b = tid; b < nbuk; b += 256) hist[b] = 0;
    __syncthreads();
#pragma unroll
    for (int j = 0; j < 8; ++j) {
        long i = base + j * 256 + tid;
        int s = 0, d = -1;
        if (i < E) {
            if (i64) { s = ((const int2*)ei)[i].x; d = ((const int2*)(ei + 2 * (long)E))[i].x; }
            else     { s = ei[i]; d = ei[(long)E + i]; }
            if ((unsigned)s >= (unsigned)N || (unsigned)d >= (unsigned)N) d = -1;
        }
        se[j] = s; de[j] = d;
        if (d >= 0) atomicAdd(&hist[d / NPB], 1);
    }
    __syncthreads();
    for (int b = tid; b < nbuk; b += 256) {
        int h = hist[b];
        gbase[b] = h > 0 ? atomicAdd(&gcur[b], h) : 0;
        hist[b] = 0;
    }
    __syncthreads();
#pragma unroll
    for (int j = 0; j < 8; ++j) {
        int d = de[j];
        if (d < 0) continue;
        int b = d / NPB;
        int p = gbase[b] + atomicAdd(&hist[b], 1);
        if (p < BCAP) {
            pairs[(long)b * BCAP + p] = ((unsigned)(d - b * NPB) << 16) | (unsigned)se[j];
        } else {
            int op = atomicAdd(ovfAcnt, 1);
            if (op < OVF_MAX) ovfA[op] = make_int2(d, se[j]);
        }
    }
}

// Phase B (u16): per bucket, build cnt+slots in LDS (incl. folding any phase-A
// overflow entries for this bucket), dense vector writeout.
__global__ __launch_bounds__(256) void k_binB(const int* __restrict__ gcur,
                                              const unsigned* __restrict__ pairs,
                                              const int2* __restrict__ ovfA,
                                              const int* __restrict__ ovfAcnt,
                                              int* __restrict__ cnt,
                                              unsigned short* __restrict__ slots,
                                              int2* __restrict__ ovf2,
                                              int* __restrict__ ovf2cnt, int N) {
    __shared__ int cntL[NPB];
    __shared__ __align__(16) unsigned short slotsL[NPB * CAP];
    const int b = blockIdx.x;
    const int tid = threadIdx.x;
    const int d0 = b * NPB;
    const int nd = min(NPB, N - d0);
    if (nd <= 0) return;
    for (int i = tid; i < NPB; i += 256) cntL[i] = 0;
    __syncthreads();
    const int c = min(gcur[b], BCAP);
    const unsigned* pb = pairs + (long)b * BCAP;
    for (int i = tid; i < c; i += 256) {
        unsigned p = pb[i];
        int ld = p >> 16;
        int pos = atomicAdd(&cntL[ld], 1);
        if (pos < CAP) {
            slotsL[ld * CAP + pos] = (unsigned short)(p & 0xffffu);
        } else {
            int op = atomicAdd(ovf2cnt, 1);
            if (op < OVF_MAX) ovf2[op] = make_int2(d0 + ld, (int)(p & 0xffffu));
        }
    }
    // fold phase-A overflow (almost always empty)
    int na = *ovfAcnt; na = na < OVF_MAX ? na : OVF_MAX;
    for (int i = tid; i < na; i += 256) {
        int2 p = ovfA[i];
        int ld = p.x - d0;
        if ((unsigned)ld < (unsigned)nd) {
            int pos = atomicAdd(&cntL[ld], 1);
            if (pos < CAP) {
                slotsL[ld * CAP + pos] = (unsigned short)p.y;
            } else {
                int op = atomicAdd(ovf2cnt, 1);
                if (op < OVF_MAX) ovf2[op] = p;
            }
        }
    }
    __syncthreads();
    for (int i = tid; i < nd; i += 256) cnt[d0 + i] = cntL[i];
    const uint4* sv = (const uint4*)slotsL;
    uint4* gv = (uint4*)(slots + (long)d0 * CAP);   // d0*CAP*2 = b*9408, 16B-aligned
    const int total8 = (nd * CAP) >> 3;             // CAP=48 divisible by 8
    for (int i = tid; i < total8; i += 256) gv[i] = sv[i];
}

// Fallback direct build for N > 65536 (int slots).
__global__ __launch_bounds__(256) void k_build_direct(const int* __restrict__ ei, int E, int N,
                                                      int* __restrict__ cnt,
                                                      int* __restrict__ slots,
                                                      int2* __restrict__ ovf2,
                                                      int* __restrict__ ovf2cnt,
                                                      const int* __restrict__ flags) {
    long i = (long)blockIdx.x * 256 + threadIdx.x;
    if (i >= E) return;
    int s, d;
    if (flags[1]) { s = ((const int2*)ei)[i].x; d = ((const int2*)(ei + 2 * (long)E))[i].x; }
    else          { s = ei[i]; d = ei[(long)E + i]; }
    if ((unsigned)s >= (unsigned)N || (unsigned)d >= (unsigned)N) return;
    int pos = atomicAdd(&cnt[d], 1);
    if (pos < CAP) {
        slots[(long)d * CAP + pos] = s;
    } else {
        int op = atomicAdd(ovf2cnt, 1);
        if (op < OVF_MAX) ovf2[op] = make_int2(d, s);
    }
}

// MFMA GEMM: G = bf16( rsqrt(cnt+1) * (X @ W) ). SPLIT=1: write as 2 column
// planes of C/2 cols (plane stride N*C/2) for L2-friendly gather passes.
template<int CT, int SPLIT>
__global__ __launch_bounds__(256) void k_gemm(const void* __restrict__ Xp, int x_follows_flag,
                                              const void* __restrict__ Wp,
                                              const int* __restrict__ cnt,
                                              __hip_bfloat16* __restrict__ G,
                                              const int* __restrict__ flags, int N) {
    constexpr int C = CT * 16;
    __shared__ __align__(16) short Wt[C * 136];   // W^T bf16, pad 128->136
    const bool f32m = flags[0] != 0;
    const bool xf32 = (x_follows_flag != 0) && f32m;
    const int tid = threadIdx.x;
    for (int i = tid; i < 128 * C; i += 256) {
        int k = i / C, n = i % C;
        float wv = f32m ? ((const float*)Wp)[(long)k * C + n]
                        : bf2f(((const __hip_bfloat16*)Wp)[(long)k * C + n]);
        Wt[n * 136 + k] = (short)f2bfu(wv);
    }
    __syncthreads();
    const int w = tid >> 6, lane = tid & 63;
    const int m = lane & 15, quad = lane >> 4;
    const int rowA = blockIdx.x * 64 + w * 16 + m;
    const int rowc = rowA < N ? rowA : N - 1;
    s16x8 afr[4];
#pragma unroll
    for (int kc = 0; kc < 4; ++kc) {
        const int k0 = kc * 32 + quad * 8;
        if (!xf32) {
            afr[kc] = *(const s16x8*)((const __hip_bfloat16*)Xp + (long)rowc * 128 + k0);
        } else {
            const float* p = (const float*)Xp + (long)rowc * 128 + k0;
            s16x8 t;
#pragma unroll
            for (int j = 0; j < 8; ++j) t[j] = (short)f2bfu(p[j]);
            afr[kc] = t;
        }
    }
    const int rbase = blockIdx.x * 64 + w * 16 + quad * 4;
    float dv[4];
#pragma unroll
    for (int r = 0; r < 4; ++r) {
        int rr = min(rbase + r, N - 1);
        dv[r] = rsqrtf((float)(cnt[rr] + 1));
    }
#pragma unroll
    for (int ct = 0; ct < CT; ++ct) {
        f32x4 acc = {0.f, 0.f, 0.f, 0.f};
#pragma unroll
        for (int kc = 0; kc < 4; ++kc) {
            s16x8 bfr = *(const s16x8*)&Wt[(ct * 16 + m) * 136 + kc * 32 + quad * 8];
            acc = __builtin_amdgcn_mfma_f32_16x16x32_bf16(afr[kc], bfr, acc, 0, 0, 0);
        }
#pragma unroll
        for (int r = 0; r < 4; ++r) {
            int rr = rbase + r;
            if (rr < N) {
                long off;
                if (SPLIT) {
                    const int plane = ct / (CT / 2);
                    const int cp = (ct % (CT / 2)) * 16 + m;
                    off = (long)plane * N * (C / 2) + (long)rr * (C / 2) + cp;
                } else {
                    off = (long)rr * C + ct * 16 + m;
                }
                G[off] = __float2bfloat16(dv[r] * acc[r]);
            }
        }
    }
}

// Half-plane gather for layer 1 (pass P of 2): reads 64-col plane (128B rows),
// writes h1[:, P*64 : P*64+64] with bias+relu. 8 lanes/node, 32 nodes/block.
__global__ __launch_bounds__(256) void k_gather_half(const __hip_bfloat16* __restrict__ Gp,
                                                     const int* __restrict__ cnt,
                                                     const unsigned short* __restrict__ slots,
                                                     const int2* __restrict__ ovf2,
                                                     const int* __restrict__ ovf2cnt,
                                                     const void* __restrict__ b1,
                                                     __hip_bfloat16* __restrict__ h1,
                                                     const int* __restrict__ flags,
                                                     int N, int P) {
    const int tid = threadIdx.x;
    const int grp = tid >> 3, lane = tid & 7;
    const int node = blockIdx.x * 32 + grp;
    if (node >= N) return;
    const int cd = cnt[node];
    const float wself = rsqrtf((float)(cd + 1));
    const int m = cd < CAP ? cd : CAP;
    const unsigned short* sl = slots + (long)node * CAP;
    float acc[8] = {0, 0, 0, 0, 0, 0, 0, 0};
    acc_add(acc, ((const uint4*)(Gp + (long)node * 64))[lane]);   // self loop
    int i = 0;
    for (; i + 7 < m; i += 8) {
        int s0 = sl[i], s1 = sl[i + 1], s2 = sl[i + 2], s3 = sl[i + 3];
        int s4 = sl[i + 4], s5 = sl[i + 5], s6 = sl[i + 6], s7 = sl[i + 7];
        uint4 v0 = ((const uint4*)(Gp + (long)s0 * 64))[lane];
        uint4 v1 = ((const uint4*)(Gp + (long)s1 * 64))[lane];
        uint4 v2 = ((const uint4*)(Gp + (long)s2 * 64))[lane];
        uint4 v3 = ((const uint4*)(Gp + (long)s3 * 64))[lane];
        uint4 v4 = ((const uint4*)(Gp + (long)s4 * 64))[lane];
        uint4 v5 = ((const uint4*)(Gp + (long)s5 * 64))[lane];
        uint4 v6 = ((const uint4*)(Gp + (long)s6 * 64))[lane];
        uint4 v7 = ((const uint4*)(Gp + (long)s7 * 64))[lane];
        acc_add(acc, v0); acc_add(acc, v1); acc_add(acc, v2); acc_add(acc, v3);
        acc_add(acc, v4); acc_add(acc, v5); acc_add(acc, v6); acc_add(acc, v7);
    }
    for (; i + 3 < m; i += 4) {
        int s0 = sl[i], s1 = sl[i + 1], s2 = sl[i + 2], s3 = sl[i + 3];
        uint4 v0 = ((const uint4*)(Gp + (long)s0 * 64))[lane];
        uint4 v1 = ((const uint4*)(Gp + (long)s1 * 64))[lane];
        uint4 v2 = ((const uint4*)(Gp + (long)s2 * 64))[lane];
        uint4 v3 = ((const uint4*)(Gp + (long)s3 * 64))[lane];
        acc_add(acc, v0); acc_add(acc, v1); acc_add(acc, v2); acc_add(acc, v3);
    }
    for (; i < m; ++i)
        acc_add(acc, ((const uint4*)(Gp + (long)sl[i] * 64))[lane]);
    if (cd > CAP) {
        int oc = *ovf2cnt; oc = oc < OVF_MAX ? oc : OVF_MAX;
        for (int j = 0; j < oc; ++j)
            if (ovf2[j].x == node)
                acc_add(acc, ((const uint4*)(Gp + (long)ovf2[j].y * 64))[lane]);
    }
    const bool f32m = flags[0] != 0;
    const int c0 = P * 64 + lane * 8;
    float bv[8];
    if (f32m) {
        const float4* bp = (const float4*)((const float*)b1 + c0);
        float4 b0 = bp[0], b1v = bp[1];
        bv[0] = b0.x; bv[1] = b0.y; bv[2] = b0.z; bv[3] = b0.w;
        bv[4] = b1v.x; bv[5] = b1v.y; bv[6] = b1v.z; bv[7] = b1v.w;
    } else {
        uint4 b = *(const uint4*)((const __hip_bfloat16*)b1 + c0);
        bv[0] = lo2f(b.x); bv[1] = hi2f(b.x); bv[2] = lo2f(b.y); bv[3] = hi2f(b.y);
        bv[4] = lo2f(b.z); bv[5] = hi2f(b.z); bv[6] = lo2f(b.w); bv[7] = hi2f(b.w);
    }
    float o[8];
#pragma unroll
    for (int c = 0; c < 8; ++c) {
        float v = wself * acc[c] + bv[c];
        o[c] = v > 0.f ? v : 0.f;
    }
    uint4 pv = { pack2(o[0], o[1]), pack2(o[2], o[3]), pack2(o[4], o[5]), pack2(o[6], o[7]) };
    ((uint4*)(h1 + (long)node * 128 + P * 64))[lane] = pv;
}

// Full-row gather (layer 2 and fallback layer 1).
template<int F, int LAYER1, typename ST>
__global__ __launch_bounds__(256) void k_gather(const __hip_bfloat16* __restrict__ G,
                                                const int* __restrict__ cnt,
                                                const ST* __restrict__ slots,
                                                const int2* __restrict__ ovf2,
                                                const int* __restrict__ ovf2cnt,
                                                const void* __restrict__ bias,
                                                void* __restrict__ outp,
                                                const int* __restrict__ flags, int N) {
    constexpr int L = F / 8;
    constexpr int NODES = 256 / L;
    const int tid = threadIdx.x;
    const int grp = tid / L, lane = tid % L;
    const int node = blockIdx.x * NODES + grp;
    if (node >= N) return;
    const int cd = cnt[node];
    const float wself = rsqrtf((float)(cd + 1));
    const int m = cd < CAP ? cd : CAP;
    const ST* sl = slots + (long)node * CAP;
    float acc[8] = {0, 0, 0, 0, 0, 0, 0, 0};
    acc_add(acc, ((const uint4*)(G + (long)node * F))[lane]);
    int i = 0;
    for (; i + 7 < m; i += 8) {
        int s0 = sl[i], s1 = sl[i + 1], s2 = sl[i + 2], s3 = sl[i + 3];
        int s4 = sl[i + 4], s5 = sl[i + 5], s6 = sl[i + 6], s7 = sl[i + 7];
        uint4 v0 = ((const uint4*)(G + (long)s0 * F))[lane];
        uint4 v1 = ((const uint4*)(G + (long)s1 * F))[lane];
        uint4 v2 = ((const uint4*)(G + (long)s2 * F))[lane];
        uint4 v3 = ((const uint4*)(G + (long)s3 * F))[lane];
        uint4 v4 = ((const uint4*)(G + (long)s4 * F))[lane];
        uint4 v5 = ((const uint4*)(G + (long)s5 * F))[lane];
        uint4 v6 = ((const uint4*)(G + (long)s6 * F))[lane];
        uint4 v7 = ((const uint4*)(G + (long)s7 * F))[lane];
        acc_add(acc, v0); acc_add(acc, v1); acc_add(acc, v2); acc_add(acc, v3);
        acc_add(acc, v4); acc_add(acc, v5); acc_add(acc, v6); acc_add(acc, v7);
    }
    for (; i + 3 < m; i += 4) {
        int s0 = sl[i], s1 = sl[i + 1], s2 = sl[i + 2], s3 = sl[i + 3];
        uint4 v0 = ((const uint4*)(G + (long)s0 * F))[lane];
        uint4 v1 = ((const uint4*)(G + (long)s1 * F))[lane];
        uint4 v2 = ((const uint4*)(G + (long)s2 * F))[lane];
        uint4 v3 = ((const uint4*)(G + (long)s3 * F))[lane];
        acc_add(acc, v0); acc_add(acc, v1); acc_add(acc, v2); acc_add(acc, v3);
    }
    for (; i < m; ++i)
        acc_add(acc, ((const uint4*)(G + (long)sl[i] * F))[lane]);
    if (cd > CAP) {
        int oc = *ovf2cnt; oc = oc < OVF_MAX ? oc : OVF_MAX;
        for (int j = 0; j < oc; ++j)
            if (ovf2[j].x == node)
                acc_add(acc, ((const uint4*)(G + (long)ovf2[j].y * F))[lane]);
    }
    const bool f32m = flags[0] != 0;
    const int c0 = lane * 8;
    float bv[8];
    if (f32m) {
        const float4* bp = (const float4*)((const float*)bias + c0);
        float4 b0 = bp[0], b1 = bp[1];
        bv[0] = b0.x; bv[1] = b0.y; bv[2] = b0.z; bv[3] = b0.w;
        bv[4] = b1.x; bv[5] = b1.y; bv[6] = b1.z; bv[7] = b1.w;
    } else {
        uint4 b = *(const uint4*)((const __hip_bfloat16*)bias + c0);
        bv[0] = lo2f(b.x); bv[1] = hi2f(b.x); bv[2] = lo2f(b.y); bv[3] = hi2f(b.y);
        bv[4] = lo2f(b.z); bv[5] = hi2f(b.z); bv[6] = lo2f(b.w); bv[7] = hi2f(b.w);
    }
    float o[8];
#pragma unroll
    for (int c = 0; c < 8; ++c) {
        float v = wself * acc[c] + bv[c];
        o[c] = (LAYER1 && v < 0.f) ? 0.f : v;
    }
    if (LAYER1 || !f32m) {
        uint4 pv = { pack2(o[0], o[1]), pack2(o[2], o[3]), pack2(o[4], o[5]), pack2(o[6], o[7]) };
        ((uint4*)outp)[(long)node * L + lane] = pv;
    } else {
        float4* op = (float4*)((float*)outp + (long)node * F + c0);
        op[0] = make_float4(o[0], o[1], o[2], o[3]);
        op[1] = make_float4(o[4], o[5], o[6], o[7]);
    }
}

extern "C" void kernel_launch(void* const* d_in, const int* in_sizes, int n_in,
                              void* d_out, int out_size, void* d_ws, size_t ws_size,
                              hipStream_t stream) {
    const void* x  = d_in[0];
    const int*  ei = (const int*)d_in[1];
    const void* W1 = d_in[2];
    const void* b1 = d_in[3];
    const void* W2 = d_in[4];
    const void* b2 = d_in[5];

    const int N = in_sizes[0] / FIN;   // 50000
    const int E = in_sizes[1] / 2;     // 800000
    const int nbuk = (N + NPB - 1) / NPB;   // 511 (<=512 supported for u16 path)

    // ws layout (bytes), peak ~37.3MB:
    //   flags @0; gcur @4096 (512 ints; [512]=ovfAcnt, [513]=ovf2cnt)
    //   cnt @65536 (4N); ovfA @524288; ovf2 @1048576
    //   slots @2097152 (u16 4.8MB / int 9.6MB; region 9.6MB)
    //   g @11730944 (12.8MB bf16, 2 planes of N*64; g2 overlays)
    //   pairs @24530944 (6.28MB; h1 overlays after binB)
    char* ws = (char*)d_ws;
    int*   flags   = (int*)ws;
    int*   gcur    = (int*)(ws + 4096);
    int*   ovfAcnt = gcur + 512;
    int*   ovf2cnt = gcur + 513;
    int*   cnt     = (int*)(ws + 65536);
    int2*  ovfA    = (int2*)(ws + 524288);
    int2*  ovf2    = (int2*)(ws + 1048576);
    unsigned short* slots16 = (unsigned short*)(ws + 2097152);
    int*   slots32 = (int*)(ws + 2097152);
    __hip_bfloat16* g  = (__hip_bfloat16*)(ws + 11730944);
    __hip_bfloat16* g2 = g;                                     // overlays g
    unsigned* pairs = (unsigned*)(ws + 24530944);
    __hip_bfloat16* h1 = (__hip_bfloat16*)(ws + 24530944);      // overlays pairs

    const int GB = (N + 63) / 64;
    const int AB = (E + 2047) / 2048;
    const int EB = (E + 255) / 256;

    k_detect<<<64, 256, 0, stream>>>((const unsigned*)x, ei, E, flags, gcur, cnt, N);

    if (N <= 65536 && nbuk <= 512) {
        k_binA<<<AB, 256, 0, stream>>>(ei, E, N, nbuk, gcur, pairs, ovfA, ovfAcnt, flags);
        k_binB<<<nbuk, 256, 0, stream>>>(gcur, pairs, ovfA, ovfAcnt, cnt, slots16, ovf2, ovf2cnt, N);
        k_gemm<8, 1><<<GB, 256, 0, stream>>>(x, 1, W1, cnt, g, flags, N);   // plane-split g
        k_gather_half<<<(N + 31) / 32, 256, 0, stream>>>(g, cnt, slots16, ovf2, ovf2cnt, b1, h1, flags, N, 0);
        k_gather_half<<<(N + 31) / 32, 256, 0, stream>>>(g + (long)N * 64, cnt, slots16, ovf2, ovf2cnt, b1, h1, flags, N, 1);
        k_gemm<4, 0><<<GB, 256, 0, stream>>>(h1, 0, W2, cnt, g2, flags, N);
        k_gather<64, 0, unsigned short><<<(N + 31) / 32, 256, 0, stream>>>(
            g2, cnt, slots16, ovf2, ovf2cnt, b2, d_out, flags, N);
    } else {
        k_build_direct<<<EB, 256, 0, stream>>>(ei, E, N, cnt, slots32, ovf2, ovf2cnt, flags);
        k_gemm<8, 0><<<GB, 256, 0, stream>>>(x, 1, W1, cnt, g, flags, N);
        k_gather<128, 1, int><<<(N + 15) / 16, 256, 0, stream>>>(
            g, cnt, slots32, ovf2, ovf2cnt, b1, h1, flags, N);
        k_gemm<4, 0><<<GB, 256, 0, stream>>>(h1, 0, W2, cnt, g2, flags, N);
        k_gather<64, 0, int><<<(N + 31) / 32, 256, 0, stream>>>(
            g2, cnt, slots32, ovf2, ovf2cnt, b2, d_out, flags, N);
    }
}

// Round 13
// 192.997 us; speedup vs baseline: 1.2121x; 1.0503x over previous
//
#include <hip/hip_runtime.h>
#include <hip/hip_bf16.h>

// GCN 2-layer encoder. R13: block-specialized mega-kernel overlaps binA
// (write-drain bound) with gemm1 (MFMA bound) in ONE dispatch — no intra-block
// barrier (R6 failure mode avoided). gemm1 emits UNscaled g; gather_half
// applies dinv[s] per source (dinv array written by binB). 1-block detect.
// out[d] = dinv[d] * sum_{s in N(d) U {d}} dinv[s]*h[s] + b,  h = in @ W1

constexpr int FIN = 128;
constexpr int HID = 128;
constexpr int FOUT = 64;
constexpr int CAP = 48;     // adjacency slots per node
constexpr int NPB = 98;     // nodes per bucket
constexpr int BCAP = 3072;  // pairs per bucket region
constexpr int OVF_MAX = 65536;

typedef __attribute__((ext_vector_type(8))) short s16x8;
typedef __attribute__((ext_vector_type(4))) float f32x4;

static __device__ __forceinline__ float bf2f(__hip_bfloat16 v) { return __bfloat162float(v); }
static __device__ __forceinline__ float lo2f(unsigned u) { union { unsigned i; float f; } c; c.i = u << 16; return c.f; }
static __device__ __forceinline__ float hi2f(unsigned u) { union { unsigned i; float f; } c; c.i = u & 0xffff0000u; return c.f; }
static __device__ __forceinline__ unsigned short f2bfu(float f) {
    __hip_bfloat16 h = __float2bfloat16(f);
    union { __hip_bfloat16 h; unsigned short u; } c; c.h = h; return c.u;
}
static __device__ __forceinline__ unsigned pack2(float a, float b) {
    return (unsigned)f2bfu(a) | ((unsigned)f2bfu(b) << 16);
}
static __device__ __forceinline__ void acc_add(float* acc, uint4 v) {
    acc[0] += lo2f(v.x); acc[1] += hi2f(v.x);
    acc[2] += lo2f(v.y); acc[3] += hi2f(v.y);
    acc[4] += lo2f(v.z); acc[5] += hi2f(v.z);
    acc[6] += lo2f(v.w); acc[7] += hi2f(v.w);
}
static __device__ __forceinline__ void acc_fma(float* acc, uint4 v, float w) {
    acc[0] += w * lo2f(v.x); acc[1] += w * hi2f(v.x);
    acc[2] += w * lo2f(v.y); acc[3] += w * hi2f(v.y);
    acc[4] += w * lo2f(v.z); acc[5] += w * hi2f(v.z);
    acc[6] += w * lo2f(v.w); acc[7] += w * hi2f(v.w);
}

// flags detect + zero gcur/ovf counters. zero_cnt!=0 (fallback path): zero cnt.
__global__ __launch_bounds__(256) void k_detect(const unsigned* __restrict__ xw,
                                                const int* __restrict__ eiw,
                                                int E, int* __restrict__ flags,
                                                int* __restrict__ gcur,
                                                int* __restrict__ cnt, int N, int zero_cnt) {
    if (zero_cnt)
        for (long i = (long)blockIdx.x * 256 + threadIdx.x; i < N; i += (long)gridDim.x * 256)
            cnt[i] = 0;
    if (blockIdx.x != 0) return;
    for (int i = threadIdx.x; i < 514; i += 256) gcur[i] = 0;
    __shared__ int s_bf16like, s_oddnz;
    if (threadIdx.x == 0) { s_bf16like = 0; s_oddnz = 0; }
    __syncthreads();
    int c = 0;
    for (int i = threadIdx.x; i < 4096; i += 256) {
        unsigned ex = ((xw[i] & 0xffffu) >> 7) & 0xffu;
        if (ex >= 117u && ex <= 130u) c++;
    }
    atomicAdd(&s_bf16like, c);
    int nz = 0;
    for (int i = threadIdx.x; i < 2048; i += 256)
        if (eiw[2 * i + 1] != 0) nz++;
    atomicAdd(&s_oddnz, nz);
    __syncthreads();
    if (threadIdx.x == 0) {
        flags[0] = (s_bf16like < 2048) ? 1 : 0;
        flags[1] = (s_oddnz == 0) ? 1 : 0;
    }
}

// Mega kernel: blocks [0,GB) = gemm1 (unscaled, plane-split g);
//              blocks [GB,GB+AB) = binA edge partition. Dynamic LDS.
__global__ __launch_bounds__(256) void k_mega(const void* __restrict__ Xp,
                                              const void* __restrict__ Wp,
                                              const int* __restrict__ ei, int E, int N,
                                              int nbuk, int GB,
                                              int* __restrict__ gcur,
                                              unsigned* __restrict__ pairs,
                                              int2* __restrict__ ovfA,
                                              int* __restrict__ ovfAcnt,
                                              __hip_bfloat16* __restrict__ G,
                                              const int* __restrict__ flags) {
    extern __shared__ __align__(16) char smem[];
    const int tid = threadIdx.x;
    if ((int)blockIdx.x < GB) {
        // ---------------- GEMM1: g = X @ W1 (unscaled), 2 column planes ----
        short* Wt = (short*)smem;                    // 128x136 bf16 = 34816 B
        const bool f32m = flags[0] != 0;
        for (int i = tid; i < 128 * 128; i += 256) {
            int k = i >> 7, n = i & 127;
            float wv = f32m ? ((const float*)Wp)[(long)k * 128 + n]
                            : bf2f(((const __hip_bfloat16*)Wp)[(long)k * 128 + n]);
            Wt[n * 136 + k] = (short)f2bfu(wv);
        }
        __syncthreads();
        const int w = tid >> 6, lane = tid & 63;
        const int m = lane & 15, quad = lane >> 4;
        const int rowA = blockIdx.x * 64 + w * 16 + m;
        const int rowc = rowA < N ? rowA : N - 1;
        s16x8 afr[4];
#pragma unroll
        for (int kc = 0; kc < 4; ++kc) {
            const int k0 = kc * 32 + quad * 8;
            if (!f32m) {
                afr[kc] = *(const s16x8*)((const __hip_bfloat16*)Xp + (long)rowc * 128 + k0);
            } else {
                const float* p = (const float*)Xp + (long)rowc * 128 + k0;
                s16x8 t;
#pragma unroll
                for (int j = 0; j < 8; ++j) t[j] = (short)f2bfu(p[j]);
                afr[kc] = t;
            }
        }
        const int rbase = blockIdx.x * 64 + w * 16 + quad * 4;
#pragma unroll
        for (int ct = 0; ct < 8; ++ct) {
            f32x4 acc = {0.f, 0.f, 0.f, 0.f};
#pragma unroll
            for (int kc = 0; kc < 4; ++kc) {
                s16x8 bfr = *(const s16x8*)&Wt[(ct * 16 + m) * 136 + kc * 32 + quad * 8];
                acc = __builtin_amdgcn_mfma_f32_16x16x32_bf16(afr[kc], bfr, acc, 0, 0, 0);
            }
            const int plane = ct >> 2;
            const int cp = (ct & 3) * 16 + m;
#pragma unroll
            for (int r = 0; r < 4; ++r) {
                int rr = rbase + r;
                if (rr < N)
                    G[(long)plane * N * 64 + (long)rr * 64 + cp] = __float2bfloat16(acc[r]);
            }
        }
    } else {
        // ---------------- binA: edge partition into buckets ----------------
        int* hist = (int*)smem;          // 512 ints
        int* gbase = hist + 512;         // 512 ints
        const long base = (long)(blockIdx.x - GB) * 2048;
        const bool i64 = flags[1] != 0;
        int se[8], de[8];
        for (int b = tid; b < nbuk; b += 256) hist[b] = 0;
        __syncthreads();
#pragma unroll
        for (int j = 0; j < 8; ++j) {
            long i = base + j * 256 + tid;
            int s = 0, d = -1;
            if (i < E) {
                if (i64) { s = ((const int2*)ei)[i].x; d = ((const int2*)(ei + 2 * (long)E))[i].x; }
                else     { s = ei[i]; d = ei[(long)E + i]; }
                if ((unsigned)s >= (unsigned)N || (unsigned)d >= (unsigned)N) d = -1;
            }
            se[j] = s; de[j] = d;
            if (d >= 0) atomicAdd(&hist[d / NPB], 1);
        }
        __syncthreads();
        for (int b = tid; b < nbuk; b += 256) {
            int h = hist[b];
            gbase[b] = h > 0 ? atomicAdd(&gcur[b], h) : 0;
            hist[b] = 0;
        }
        __syncthreads();
#pragma unroll
        for (int j = 0; j < 8; ++j) {
            int d = de[j];
            if (d < 0) continue;
            int b = d / NPB;
            int p = gbase[b] + atomicAdd(&hist[b], 1);
            if (p < BCAP) {
                pairs[(long)b * BCAP + p] = ((unsigned)(d - b * NPB) << 16) | (unsigned)se[j];
            } else {
                int op = atomicAdd(ovfAcnt, 1);
                if (op < OVF_MAX) ovfA[op] = make_int2(d, se[j]);
            }
        }
    }
}

// Phase B: per bucket, build cnt+slots+dinv in LDS (incl. phase-A ovf fold).
__global__ __launch_bounds__(256) void k_binB(const int* __restrict__ gcur,
                                              const unsigned* __restrict__ pairs,
                                              const int2* __restrict__ ovfA,
                                              const int* __restrict__ ovfAcnt,
                                              int* __restrict__ cnt,
                                              float* __restrict__ dinv,
                                              unsigned short* __restrict__ slots,
                                              int2* __restrict__ ovf2,
                                              int* __restrict__ ovf2cnt, int N) {
    __shared__ int cntL[NPB];
    __shared__ __align__(16) unsigned short slotsL[NPB * CAP];
    const int b = blockIdx.x;
    const int tid = threadIdx.x;
    const int d0 = b * NPB;
    const int nd = min(NPB, N - d0);
    if (nd <= 0) return;
    for (int i = tid; i < NPB; i += 256) cntL[i] = 0;
    __syncthreads();
    const int c = min(gcur[b], BCAP);
    const unsigned* pb = pairs + (long)b * BCAP;
    for (int i = tid; i < c; i += 256) {
        unsigned p = pb[i];
        int ld = p >> 16;
        int pos = atomicAdd(&cntL[ld], 1);
        if (pos < CAP) {
            slotsL[ld * CAP + pos] = (unsigned short)(p & 0xffffu);
        } else {
            int op = atomicAdd(ovf2cnt, 1);
            if (op < OVF_MAX) ovf2[op] = make_int2(d0 + ld, (int)(p & 0xffffu));
        }
    }
    int na = *ovfAcnt; na = na < OVF_MAX ? na : OVF_MAX;
    for (int i = tid; i < na; i += 256) {
        int2 p = ovfA[i];
        int ld = p.x - d0;
        if ((unsigned)ld < (unsigned)nd) {
            int pos = atomicAdd(&cntL[ld], 1);
            if (pos < CAP) {
                slotsL[ld * CAP + pos] = (unsigned short)p.y;
            } else {
                int op = atomicAdd(ovf2cnt, 1);
                if (op < OVF_MAX) ovf2[op] = p;
            }
        }
    }
    __syncthreads();
    for (int i = tid; i < nd; i += 256) {
        cnt[d0 + i] = cntL[i];
        dinv[d0 + i] = rsqrtf((float)(cntL[i] + 1));
    }
    const uint4* sv = (const uint4*)slotsL;
    uint4* gv = (uint4*)(slots + (long)d0 * CAP);
    const int total8 = (nd * CAP) >> 3;
    for (int i = tid; i < total8; i += 256) gv[i] = sv[i];
}

// Fallback direct build for N > 65536 (int slots). cnt must be pre-zeroed.
__global__ __launch_bounds__(256) void k_build_direct(const int* __restrict__ ei, int E, int N,
                                                      int* __restrict__ cnt,
                                                      int* __restrict__ slots,
                                                      int2* __restrict__ ovf2,
                                                      int* __restrict__ ovf2cnt,
                                                      const int* __restrict__ flags) {
    long i = (long)blockIdx.x * 256 + threadIdx.x;
    if (i >= E) return;
    int s, d;
    if (flags[1]) { s = ((const int2*)ei)[i].x; d = ((const int2*)(ei + 2 * (long)E))[i].x; }
    else          { s = ei[i]; d = ei[(long)E + i]; }
    if ((unsigned)s >= (unsigned)N || (unsigned)d >= (unsigned)N) return;
    int pos = atomicAdd(&cnt[d], 1);
    if (pos < CAP) {
        slots[(long)d * CAP + pos] = s;
    } else {
        int op = atomicAdd(ovf2cnt, 1);
        if (op < OVF_MAX) ovf2[op] = make_int2(d, s);
    }
}

// Scaled MFMA GEMM (runs after binB): G = bf16( rsqrt(cnt+1) * (X @ W) ).
template<int CT, int SPLIT>
__global__ __launch_bounds__(256) void k_gemm(const void* __restrict__ Xp, int x_follows_flag,
                                              const void* __restrict__ Wp,
                                              const int* __restrict__ cnt,
                                              __hip_bfloat16* __restrict__ G,
                                              const int* __restrict__ flags, int N) {
    constexpr int C = CT * 16;
    __shared__ __align__(16) short Wt[C * 136];
    const bool f32m = flags[0] != 0;
    const bool xf32 = (x_follows_flag != 0) && f32m;
    const int tid = threadIdx.x;
    for (int i = tid; i < 128 * C; i += 256) {
        int k = i / C, n = i % C;
        float wv = f32m ? ((const float*)Wp)[(long)k * C + n]
                        : bf2f(((const __hip_bfloat16*)Wp)[(long)k * C + n]);
        Wt[n * 136 + k] = (short)f2bfu(wv);
    }
    __syncthreads();
    const int w = tid >> 6, lane = tid & 63;
    const int m = lane & 15, quad = lane >> 4;
    const int rowA = blockIdx.x * 64 + w * 16 + m;
    const int rowc = rowA < N ? rowA : N - 1;
    s16x8 afr[4];
#pragma unroll
    for (int kc = 0; kc < 4; ++kc) {
        const int k0 = kc * 32 + quad * 8;
        if (!xf32) {
            afr[kc] = *(const s16x8*)((const __hip_bfloat16*)Xp + (long)rowc * 128 + k0);
        } else {
            const float* p = (const float*)Xp + (long)rowc * 128 + k0;
            s16x8 t;
#pragma unroll
            for (int j = 0; j < 8; ++j) t[j] = (short)f2bfu(p[j]);
            afr[kc] = t;
        }
    }
    const int rbase = blockIdx.x * 64 + w * 16 + quad * 4;
    float dv[4];
#pragma unroll
    for (int r = 0; r < 4; ++r) {
        int rr = min(rbase + r, N - 1);
        dv[r] = rsqrtf((float)(cnt[rr] + 1));
    }
#pragma unroll
    for (int ct = 0; ct < CT; ++ct) {
        f32x4 acc = {0.f, 0.f, 0.f, 0.f};
#pragma unroll
        for (int kc = 0; kc < 4; ++kc) {
            s16x8 bfr = *(const s16x8*)&Wt[(ct * 16 + m) * 136 + kc * 32 + quad * 8];
            acc = __builtin_amdgcn_mfma_f32_16x16x32_bf16(afr[kc], bfr, acc, 0, 0, 0);
        }
#pragma unroll
        for (int r = 0; r < 4; ++r) {
            int rr = rbase + r;
            if (rr < N) {
                long off;
                if (SPLIT) {
                    const int plane = ct / (CT / 2);
                    const int cp = (ct % (CT / 2)) * 16 + m;
                    off = (long)plane * N * (C / 2) + (long)rr * (C / 2) + cp;
                } else {
                    off = (long)rr * C + ct * 16 + m;
                }
                G[off] = __float2bfloat16(dv[r] * acc[r]);
            }
        }
    }
}

// Half-plane gather, layer 1, pass P: g is UNscaled -> apply dinv[s] per source.
// h1[:, P*64+..] = relu( dinv[d]*(dinv[d]*g[d] + sum dinv[s]*g[s]) + b1 )
__global__ __launch_bounds__(256) void k_gather_half(const __hip_bfloat16* __restrict__ Gp,
                                                     const int* __restrict__ cnt,
                                                     const float* __restrict__ dinv,
                                                     const unsigned short* __restrict__ slots,
                                                     const int2* __restrict__ ovf2,
                                                     const int* __restrict__ ovf2cnt,
                                                     const void* __restrict__ b1,
                                                     __hip_bfloat16* __restrict__ h1,
                                                     const int* __restrict__ flags,
                                                     int N, int P) {
    const int tid = threadIdx.x;
    const int grp = tid >> 3, lane = tid & 7;
    const int node = blockIdx.x * 32 + grp;
    if (node >= N) return;
    const int cd = cnt[node];
    const float wself = dinv[node];
    const int m = cd < CAP ? cd : CAP;
    const unsigned short* sl = slots + (long)node * CAP;
    float acc[8] = {0, 0, 0, 0, 0, 0, 0, 0};
    acc_fma(acc, ((const uint4*)(Gp + (long)node * 64))[lane], wself);   // self loop
    int i = 0;
    for (; i + 7 < m; i += 8) {
        int s0 = sl[i], s1 = sl[i + 1], s2 = sl[i + 2], s3 = sl[i + 3];
        int s4 = sl[i + 4], s5 = sl[i + 5], s6 = sl[i + 6], s7 = sl[i + 7];
        float w0 = dinv[s0], w1 = dinv[s1], w2 = dinv[s2], w3 = dinv[s3];
        float w4 = dinv[s4], w5 = dinv[s5], w6 = dinv[s6], w7 = dinv[s7];
        uint4 v0 = ((const uint4*)(Gp + (long)s0 * 64))[lane];
        uint4 v1 = ((const uint4*)(Gp + (long)s1 * 64))[lane];
        uint4 v2 = ((const uint4*)(Gp + (long)s2 * 64))[lane];
        uint4 v3 = ((const uint4*)(Gp + (long)s3 * 64))[lane];
        uint4 v4 = ((const uint4*)(Gp + (long)s4 * 64))[lane];
        uint4 v5 = ((const uint4*)(Gp + (long)s5 * 64))[lane];
        uint4 v6 = ((const uint4*)(Gp + (long)s6 * 64))[lane];
        uint4 v7 = ((const uint4*)(Gp + (long)s7 * 64))[lane];
        acc_fma(acc, v0, w0); acc_fma(acc, v1, w1); acc_fma(acc, v2, w2); acc_fma(acc, v3, w3);
        acc_fma(acc, v4, w4); acc_fma(acc, v5, w5); acc_fma(acc, v6, w6); acc_fma(acc, v7, w7);
    }
    for (; i + 3 < m; i += 4) {
        int s0 = sl[i], s1 = sl[i + 1], s2 = sl[i + 2], s3 = sl[i + 3];
        float w0 = dinv[s0], w1 = dinv[s1], w2 = dinv[s2], w3 = dinv[s3];
        uint4 v0 = ((const uint4*)(Gp + (long)s0 * 64))[lane];
        uint4 v1 = ((const uint4*)(Gp + (long)s1 * 64))[lane];
        uint4 v2 = ((const uint4*)(Gp + (long)s2 * 64))[lane];
        uint4 v3 = ((const uint4*)(Gp + (long)s3 * 64))[lane];
        acc_fma(acc, v0, w0); acc_fma(acc, v1, w1); acc_fma(acc, v2, w2); acc_fma(acc, v3, w3);
    }
    for (; i < m; ++i) {
        int s0 = sl[i];
        acc_fma(acc, ((const uint4*)(Gp + (long)s0 * 64))[lane], dinv[s0]);
    }
    if (cd > CAP) {
        int oc = *ovf2cnt; oc = oc < OVF_MAX ? oc : OVF_MAX;
        for (int j = 0; j < oc; ++j)
            if (ovf2[j].x == node) {
                int s0 = ovf2[j].y;
                acc_fma(acc, ((const uint4*)(Gp + (long)s0 * 64))[lane], dinv[s0]);
            }
    }
    const bool f32m = flags[0] != 0;
    const int c0 = P * 64 + lane * 8;
    float bv[8];
    if (f32m) {
        const float4* bp = (const float4*)((const float*)b1 + c0);
        float4 b0 = bp[0], b1v = bp[1];
        bv[0] = b0.x; bv[1] = b0.y; bv[2] = b0.z; bv[3] = b0.w;
        bv[4] = b1v.x; bv[5] = b1v.y; bv[6] = b1v.z; bv[7] = b1v.w;
    } else {
        uint4 b = *(const uint4*)((const __hip_bfloat16*)b1 + c0);
        bv[0] = lo2f(b.x); bv[1] = hi2f(b.x); bv[2] = lo2f(b.y); bv[3] = hi2f(b.y);
        bv[4] = lo2f(b.z); bv[5] = hi2f(b.z); bv[6] = lo2f(b.w); bv[7] = hi2f(b.w);
    }
    float o[8];
#pragma unroll
    for (int c = 0; c < 8; ++c) {
        float v = wself * acc[c] + bv[c];
        o[c] = v > 0.f ? v : 0.f;
    }
    uint4 pv = { pack2(o[0], o[1]), pack2(o[2], o[3]), pack2(o[4], o[5]), pack2(o[6], o[7]) };
    ((uint4*)(h1 + (long)node * 128 + P * 64))[lane] = pv;
}

// Full-row gather over pre-scaled G (layer 2 and fallback layer 1).
template<int F, int LAYER1, typename ST>
__global__ __launch_bounds__(256) void k_gather(const __hip_bfloat16* __restrict__ G,
                                                const int* __restrict__ cnt,
                                                const ST* __restrict__ slots,
                                                const int2* __restrict__ ovf2,
                                                const int* __restrict__ ovf2cnt,
                                                const void* __restrict__ bias,
                                                void* __restrict__ outp,
                                                const int* __restrict__ flags, int N) {
    constexpr int L = F / 8;
    constexpr int NODES = 256 / L;
    const int tid = threadIdx.x;
    const int grp = tid / L, lane = tid % L;
    const int node = blockIdx.x * NODES + grp;
    if (node >= N) return;
    const int cd = cnt[node];
    const float wself = rsqrtf((float)(cd + 1));
    const int m = cd < CAP ? cd : CAP;
    const ST* sl = slots + (long)node * CAP;
    float acc[8] = {0, 0, 0, 0, 0, 0, 0, 0};
    acc_add(acc, ((const uint4*)(G + (long)node * F))[lane]);
    int i = 0;
    for (; i + 7 < m; i += 8) {
        int s0 = sl[i], s1 = sl[i + 1], s2 = sl[i + 2], s3 = sl[i + 3];
        int s4 = sl[i + 4], s5 = sl[i + 5], s6 = sl[i + 6], s7 = sl[i + 7];
        uint4 v0 = ((const uint4*)(G + (long)s0 * F))[lane];
        uint4 v1 = ((const uint4*)(G + (long)s1 * F))[lane];
        uint4 v2 = ((const uint4*)(G + (long)s2 * F))[lane];
        uint4 v3 = ((const uint4*)(G + (long)s3 * F))[lane];
        uint4 v4 = ((const uint4*)(G + (long)s4 * F))[lane];
        uint4 v5 = ((const uint4*)(G + (long)s5 * F))[lane];
        uint4 v6 = ((const uint4*)(G + (long)s6 * F))[lane];
        uint4 v7 = ((const uint4*)(G + (long)s7 * F))[lane];
        acc_add(acc, v0); acc_add(acc, v1); acc_add(acc, v2); acc_add(acc, v3);
        acc_add(acc, v4); acc_add(acc, v5); acc_add(acc, v6); acc_add(acc, v7);
    }
    for (; i + 3 < m; i += 4) {
        int s0 = sl[i], s1 = sl[i + 1], s2 = sl[i + 2], s3 = sl[i + 3];
        uint4 v0 = ((const uint4*)(G + (long)s0 * F))[lane];
        uint4 v1 = ((const uint4*)(G + (long)s1 * F))[lane];
        uint4 v2 = ((const uint4*)(G + (long)s2 * F))[lane];
        uint4 v3 = ((const uint4*)(G + (long)s3 * F))[lane];
        acc_add(acc, v0); acc_add(acc, v1); acc_add(acc, v2); acc_add(acc, v3);
    }
    for (; i < m; ++i)
        acc_add(acc, ((const uint4*)(G + (long)sl[i] * F))[lane]);
    if (cd > CAP) {
        int oc = *ovf2cnt; oc = oc < OVF_MAX ? oc : OVF_MAX;
        for (int j = 0; j < oc; ++j)
            if (ovf2[j].x == node)
                acc_add(acc, ((const uint4*)(G + (long)ovf2[j].y * F))[lane]);
    }
    const bool f32m = flags[0] != 0;
    const int c0 = lane * 8;
    float bv[8];
    if (f32m) {
        const float4* bp = (const float4*)((const float*)bias + c0);
        float4 b0 = bp[0], b1 = bp[1];
        bv[0] = b0.x; bv[1] = b0.y; bv[2] = b0.z; bv[3] = b0.w;
        bv[4] = b1.x; bv[5] = b1.y; bv[6] = b1.z; bv[7] = b1.w;
    } else {
        uint4 b = *(const uint4*)((const __hip_bfloat16*)bias + c0);
        bv[0] = lo2f(b.x); bv[1] = hi2f(b.x); bv[2] = lo2f(b.y); bv[3] = hi2f(b.y);
        bv[4] = lo2f(b.z); bv[5] = hi2f(b.z); bv[6] = lo2f(b.w); bv[7] = hi2f(b.w);
    }
    float o[8];
#pragma unroll
    for (int c = 0; c < 8; ++c) {
        float v = wself * acc[c] + bv[c];
        o[c] = (LAYER1 && v < 0.f) ? 0.f : v;
    }
    if (LAYER1 || !f32m) {
        uint4 pv = { pack2(o[0], o[1]), pack2(o[2], o[3]), pack2(o[4], o[5]), pack2(o[6], o[7]) };
        ((uint4*)outp)[(long)node * L + lane] = pv;
    } else {
        float4* op = (float4*)((float*)outp + (long)node * F + c0);
        op[0] = make_float4(o[0], o[1], o[2], o[3]);
        op[1] = make_float4(o[4], o[5], o[6], o[7]);
    }
}

extern "C" void kernel_launch(void* const* d_in, const int* in_sizes, int n_in,
                              void* d_out, int out_size, void* d_ws, size_t ws_size,
                              hipStream_t stream) {
    const void* x  = d_in[0];
    const int*  ei = (const int*)d_in[1];
    const void* W1 = d_in[2];
    const void* b1 = d_in[3];
    const void* W2 = d_in[4];
    const void* b2 = d_in[5];

    const int N = in_sizes[0] / FIN;   // 50000
    const int E = in_sizes[1] / 2;     // 800000
    const int nbuk = (N + NPB - 1) / NPB;   // 511 (<=512 for u16 path)

    // ws layout (bytes), peak ~37.3MB:
    //   flags @0; gcur @4096 (512+2 ints)
    //   cnt @65536 (4N, ends 265536); dinv @266240 (4N, ends 466240)
    //   ovfA @524288; ovf2 @1048576
    //   slots @2097152 (u16 4.8MB / int 9.6MB)
    //   g @11730944 (12.8MB, 2 planes of N*64; g2 overlays)
    //   pairs @24530944 (6.28MB; h1 overlays after binB)
    char* ws = (char*)d_ws;
    int*   flags   = (int*)ws;
    int*   gcur    = (int*)(ws + 4096);
    int*   ovfAcnt = gcur + 512;
    int*   ovf2cnt = gcur + 513;
    int*   cnt     = (int*)(ws + 65536);
    float* dinv    = (float*)(ws + 266240);
    int2*  ovfA    = (int2*)(ws + 524288);
    int2*  ovf2    = (int2*)(ws + 1048576);
    unsigned short* slots16 = (unsigned short*)(ws + 2097152);
    int*   slots32 = (int*)(ws + 2097152);
    __hip_bfloat16* g  = (__hip_bfloat16*)(ws + 11730944);
    __hip_bfloat16* g2 = g;
    unsigned* pairs = (unsigned*)(ws + 24530944);
    __hip_bfloat16* h1 = (__hip_bfloat16*)(ws + 24530944);

    const int GB = (N + 63) / 64;
    const int AB = (E + 2047) / 2048;
    const int EB = (E + 255) / 256;

    if (N <= 65536 && nbuk <= 512) {
        k_detect<<<1, 256, 0, stream>>>((const unsigned*)x, ei, E, flags, gcur, cnt, N, 0);
        k_mega<<<GB + AB, 256, 34816, stream>>>(x, W1, ei, E, N, nbuk, GB,
                                                gcur, pairs, ovfA, ovfAcnt, g, flags);
        k_binB<<<nbuk, 256, 0, stream>>>(gcur, pairs, ovfA, ovfAcnt, cnt, dinv, slots16, ovf2, ovf2cnt, N);
        k_gather_half<<<(N + 31) / 32, 256, 0, stream>>>(g, cnt, dinv, slots16, ovf2, ovf2cnt, b1, h1, flags, N, 0);
        k_gather_half<<<(N + 31) / 32, 256, 0, stream>>>(g + (long)N * 64, cnt, dinv, slots16, ovf2, ovf2cnt, b1, h1, flags, N, 1);
        k_gemm<4, 0><<<GB, 256, 0, stream>>>(h1, 0, W2, cnt, g2, flags, N);
        k_gather<64, 0, unsigned short><<<(N + 31) / 32, 256, 0, stream>>>(
            g2, cnt, slots16, ovf2, ovf2cnt, b2, d_out, flags, N);
    } else {
        k_detect<<<64, 256, 0, stream>>>((const unsigned*)x, ei, E, flags, gcur, cnt, N, 1);
        k_build_direct<<<EB, 256, 0, stream>>>(ei, E, N, cnt, slots32, ovf2, ovf2cnt, flags);
        k_gemm<8, 0><<<GB, 256, 0, stream>>>(x, 1, W1, cnt, g, flags, N);
        k_gather<128, 1, int><<<(N + 15) / 16, 256, 0, stream>>>(
            g, cnt, slots32, ovf2, ovf2cnt, b1, h1, flags, N);
        k_gemm<4, 0><<<GB, 256, 0, stream>>>(h1, 0, W2, cnt, g2, flags, N);
        k_gather<64, 0, int><<<(N + 31) / 32, 256, 0, stream>>>(
            g2, cnt, slots32, ovf2, ovf2cnt, b2, d_out, flags, N);
    }
}

// Round 14
// 189.273 us; speedup vs baseline: 1.2359x; 1.0197x over previous
//
#include <hip/hip_runtime.h>
#include <hip/hip_bf16.h>

// GCN 2-layer encoder. R14: single-dispatch dual-plane gather1 (plane = block
// range, plane-0 blocks first -> temporal L2 split retained, one fewer launch
// gap + boundary overlap). Otherwise identical to R13: block-specialized
// mega-kernel (binA || gemm1), bucketed u16 CSR build, MFMA GEMMs.
// out[d] = dinv[d] * sum_{s in N(d) U {d}} dinv[s]*h[s] + b,  h = in @ W1

constexpr int FIN = 128;
constexpr int HID = 128;
constexpr int FOUT = 64;
constexpr int CAP = 48;     // adjacency slots per node
constexpr int NPB = 98;     // nodes per bucket
constexpr int BCAP = 3072;  // pairs per bucket region
constexpr int OVF_MAX = 65536;

typedef __attribute__((ext_vector_type(8))) short s16x8;
typedef __attribute__((ext_vector_type(4))) float f32x4;

static __device__ __forceinline__ float bf2f(__hip_bfloat16 v) { return __bfloat162float(v); }
static __device__ __forceinline__ float lo2f(unsigned u) { union { unsigned i; float f; } c; c.i = u << 16; return c.f; }
static __device__ __forceinline__ float hi2f(unsigned u) { union { unsigned i; float f; } c; c.i = u & 0xffff0000u; return c.f; }
static __device__ __forceinline__ unsigned short f2bfu(float f) {
    __hip_bfloat16 h = __float2bfloat16(f);
    union { __hip_bfloat16 h; unsigned short u; } c; c.h = h; return c.u;
}
static __device__ __forceinline__ unsigned pack2(float a, float b) {
    return (unsigned)f2bfu(a) | ((unsigned)f2bfu(b) << 16);
}
static __device__ __forceinline__ void acc_add(float* acc, uint4 v) {
    acc[0] += lo2f(v.x); acc[1] += hi2f(v.x);
    acc[2] += lo2f(v.y); acc[3] += hi2f(v.y);
    acc[4] += lo2f(v.z); acc[5] += hi2f(v.z);
    acc[6] += lo2f(v.w); acc[7] += hi2f(v.w);
}
static __device__ __forceinline__ void acc_fma(float* acc, uint4 v, float w) {
    acc[0] += w * lo2f(v.x); acc[1] += w * hi2f(v.x);
    acc[2] += w * lo2f(v.y); acc[3] += w * hi2f(v.y);
    acc[4] += w * lo2f(v.z); acc[5] += w * hi2f(v.z);
    acc[6] += w * lo2f(v.w); acc[7] += w * hi2f(v.w);
}

// flags detect + zero gcur/ovf counters. zero_cnt!=0 (fallback path): zero cnt.
__global__ __launch_bounds__(256) void k_detect(const unsigned* __restrict__ xw,
                                                const int* __restrict__ eiw,
                                                int E, int* __restrict__ flags,
                                                int* __restrict__ gcur,
                                                int* __restrict__ cnt, int N, int zero_cnt) {
    if (zero_cnt)
        for (long i = (long)blockIdx.x * 256 + threadIdx.x; i < N; i += (long)gridDim.x * 256)
            cnt[i] = 0;
    if (blockIdx.x != 0) return;
    for (int i = threadIdx.x; i < 514; i += 256) gcur[i] = 0;
    __shared__ int s_bf16like, s_oddnz;
    if (threadIdx.x == 0) { s_bf16like = 0; s_oddnz = 0; }
    __syncthreads();
    int c = 0;
    for (int i = threadIdx.x; i < 4096; i += 256) {
        unsigned ex = ((xw[i] & 0xffffu) >> 7) & 0xffu;
        if (ex >= 117u && ex <= 130u) c++;
    }
    atomicAdd(&s_bf16like, c);
    int nz = 0;
    for (int i = threadIdx.x; i < 2048; i += 256)
        if (eiw[2 * i + 1] != 0) nz++;
    atomicAdd(&s_oddnz, nz);
    __syncthreads();
    if (threadIdx.x == 0) {
        flags[0] = (s_bf16like < 2048) ? 1 : 0;
        flags[1] = (s_oddnz == 0) ? 1 : 0;
    }
}

// Mega kernel: blocks [0,GB) = gemm1 (unscaled, plane-split g);
//              blocks [GB,GB+AB) = binA edge partition. Dynamic LDS.
__global__ __launch_bounds__(256) void k_mega(const void* __restrict__ Xp,
                                              const void* __restrict__ Wp,
                                              const int* __restrict__ ei, int E, int N,
                                              int nbuk, int GB,
                                              int* __restrict__ gcur,
                                              unsigned* __restrict__ pairs,
                                              int2* __restrict__ ovfA,
                                              int* __restrict__ ovfAcnt,
                                              __hip_bfloat16* __restrict__ G,
                                              const int* __restrict__ flags) {
    extern __shared__ __align__(16) char smem[];
    const int tid = threadIdx.x;
    if ((int)blockIdx.x < GB) {
        // ---------------- GEMM1: g = X @ W1 (unscaled), 2 column planes ----
        short* Wt = (short*)smem;                    // 128x136 bf16 = 34816 B
        const bool f32m = flags[0] != 0;
        for (int i = tid; i < 128 * 128; i += 256) {
            int k = i >> 7, n = i & 127;
            float wv = f32m ? ((const float*)Wp)[(long)k * 128 + n]
                            : bf2f(((const __hip_bfloat16*)Wp)[(long)k * 128 + n]);
            Wt[n * 136 + k] = (short)f2bfu(wv);
        }
        __syncthreads();
        const int w = tid >> 6, lane = tid & 63;
        const int m = lane & 15, quad = lane >> 4;
        const int rowA = blockIdx.x * 64 + w * 16 + m;
        const int rowc = rowA < N ? rowA : N - 1;
        s16x8 afr[4];
#pragma unroll
        for (int kc = 0; kc < 4; ++kc) {
            const int k0 = kc * 32 + quad * 8;
            if (!f32m) {
                afr[kc] = *(const s16x8*)((const __hip_bfloat16*)Xp + (long)rowc * 128 + k0);
            } else {
                const float* p = (const float*)Xp + (long)rowc * 128 + k0;
                s16x8 t;
#pragma unroll
                for (int j = 0; j < 8; ++j) t[j] = (short)f2bfu(p[j]);
                afr[kc] = t;
            }
        }
        const int rbase = blockIdx.x * 64 + w * 16 + quad * 4;
#pragma unroll
        for (int ct = 0; ct < 8; ++ct) {
            f32x4 acc = {0.f, 0.f, 0.f, 0.f};
#pragma unroll
            for (int kc = 0; kc < 4; ++kc) {
                s16x8 bfr = *(const s16x8*)&Wt[(ct * 16 + m) * 136 + kc * 32 + quad * 8];
                acc = __builtin_amdgcn_mfma_f32_16x16x32_bf16(afr[kc], bfr, acc, 0, 0, 0);
            }
            const int plane = ct >> 2;
            const int cp = (ct & 3) * 16 + m;
#pragma unroll
            for (int r = 0; r < 4; ++r) {
                int rr = rbase + r;
                if (rr < N)
                    G[(long)plane * N * 64 + (long)rr * 64 + cp] = __float2bfloat16(acc[r]);
            }
        }
    } else {
        // ---------------- binA: edge partition into buckets ----------------
        int* hist = (int*)smem;          // 512 ints
        int* gbase = hist + 512;         // 512 ints
        const long base = (long)(blockIdx.x - GB) * 2048;
        const bool i64 = flags[1] != 0;
        int se[8], de[8];
        for (int b = tid; b < nbuk; b += 256) hist[b] = 0;
        __syncthreads();
#pragma unroll
        for (int j = 0; j < 8; ++j) {
            long i = base + j * 256 + tid;
            int s = 0, d = -1;
            if (i < E) {
                if (i64) { s = ((const int2*)ei)[i].x; d = ((const int2*)(ei + 2 * (long)E))[i].x; }
                else     { s = ei[i]; d = ei[(long)E + i]; }
                if ((unsigned)s >= (unsigned)N || (unsigned)d >= (unsigned)N) d = -1;
            }
            se[j] = s; de[j] = d;
            if (d >= 0) atomicAdd(&hist[d / NPB], 1);
        }
        __syncthreads();
        for (int b = tid; b < nbuk; b += 256) {
            int h = hist[b];
            gbase[b] = h > 0 ? atomicAdd(&gcur[b], h) : 0;
            hist[b] = 0;
        }
        __syncthreads();
#pragma unroll
        for (int j = 0; j < 8; ++j) {
            int d = de[j];
            if (d < 0) continue;
            int b = d / NPB;
            int p = gbase[b] + atomicAdd(&hist[b], 1);
            if (p < BCAP) {
                pairs[(long)b * BCAP + p] = ((unsigned)(d - b * NPB) << 16) | (unsigned)se[j];
            } else {
                int op = atomicAdd(ovfAcnt, 1);
                if (op < OVF_MAX) ovfA[op] = make_int2(d, se[j]);
            }
        }
    }
}

// Phase B: per bucket, build cnt+slots+dinv in LDS (incl. phase-A ovf fold).
__global__ __launch_bounds__(256) void k_binB(const int* __restrict__ gcur,
                                              const unsigned* __restrict__ pairs,
                                              const int2* __restrict__ ovfA,
                                              const int* __restrict__ ovfAcnt,
                                              int* __restrict__ cnt,
                                              float* __restrict__ dinv,
                                              unsigned short* __restrict__ slots,
                                              int2* __restrict__ ovf2,
                                              int* __restrict__ ovf2cnt, int N) {
    __shared__ int cntL[NPB];
    __shared__ __align__(16) unsigned short slotsL[NPB * CAP];
    const int b = blockIdx.x;
    const int tid = threadIdx.x;
    const int d0 = b * NPB;
    const int nd = min(NPB, N - d0);
    if (nd <= 0) return;
    for (int i = tid; i < NPB; i += 256) cntL[i] = 0;
    __syncthreads();
    const int c = min(gcur[b], BCAP);
    const unsigned* pb = pairs + (long)b * BCAP;
    for (int i = tid; i < c; i += 256) {
        unsigned p = pb[i];
        int ld = p >> 16;
        int pos = atomicAdd(&cntL[ld], 1);
        if (pos < CAP) {
            slotsL[ld * CAP + pos] = (unsigned short)(p & 0xffffu);
        } else {
            int op = atomicAdd(ovf2cnt, 1);
            if (op < OVF_MAX) ovf2[op] = make_int2(d0 + ld, (int)(p & 0xffffu));
        }
    }
    int na = *ovfAcnt; na = na < OVF_MAX ? na : OVF_MAX;
    for (int i = tid; i < na; i += 256) {
        int2 p = ovfA[i];
        int ld = p.x - d0;
        if ((unsigned)ld < (unsigned)nd) {
            int pos = atomicAdd(&cntL[ld], 1);
            if (pos < CAP) {
                slotsL[ld * CAP + pos] = (unsigned short)p.y;
            } else {
                int op = atomicAdd(ovf2cnt, 1);
                if (op < OVF_MAX) ovf2[op] = p;
            }
        }
    }
    __syncthreads();
    for (int i = tid; i < nd; i += 256) {
        cnt[d0 + i] = cntL[i];
        dinv[d0 + i] = rsqrtf((float)(cntL[i] + 1));
    }
    const uint4* sv = (const uint4*)slotsL;
    uint4* gv = (uint4*)(slots + (long)d0 * CAP);
    const int total8 = (nd * CAP) >> 3;
    for (int i = tid; i < total8; i += 256) gv[i] = sv[i];
}

// Fallback direct build for N > 65536 (int slots). cnt must be pre-zeroed.
__global__ __launch_bounds__(256) void k_build_direct(const int* __restrict__ ei, int E, int N,
                                                      int* __restrict__ cnt,
                                                      int* __restrict__ slots,
                                                      int2* __restrict__ ovf2,
                                                      int* __restrict__ ovf2cnt,
                                                      const int* __restrict__ flags) {
    long i = (long)blockIdx.x * 256 + threadIdx.x;
    if (i >= E) return;
    int s, d;
    if (flags[1]) { s = ((const int2*)ei)[i].x; d = ((const int2*)(ei + 2 * (long)E))[i].x; }
    else          { s = ei[i]; d = ei[(long)E + i]; }
    if ((unsigned)s >= (unsigned)N || (unsigned)d >= (unsigned)N) return;
    int pos = atomicAdd(&cnt[d], 1);
    if (pos < CAP) {
        slots[(long)d * CAP + pos] = s;
    } else {
        int op = atomicAdd(ovf2cnt, 1);
        if (op < OVF_MAX) ovf2[op] = make_int2(d, s);
    }
}

// Scaled MFMA GEMM (runs after binB): G = bf16( rsqrt(cnt+1) * (X @ W) ).
template<int CT, int SPLIT>
__global__ __launch_bounds__(256) void k_gemm(const void* __restrict__ Xp, int x_follows_flag,
                                              const void* __restrict__ Wp,
                                              const int* __restrict__ cnt,
                                              __hip_bfloat16* __restrict__ G,
                                              const int* __restrict__ flags, int N) {
    constexpr int C = CT * 16;
    __shared__ __align__(16) short Wt[C * 136];
    const bool f32m = flags[0] != 0;
    const bool xf32 = (x_follows_flag != 0) && f32m;
    const int tid = threadIdx.x;
    for (int i = tid; i < 128 * C; i += 256) {
        int k = i / C, n = i % C;
        float wv = f32m ? ((const float*)Wp)[(long)k * C + n]
                        : bf2f(((const __hip_bfloat16*)Wp)[(long)k * C + n]);
        Wt[n * 136 + k] = (short)f2bfu(wv);
    }
    __syncthreads();
    const int w = tid >> 6, lane = tid & 63;
    const int m = lane & 15, quad = lane >> 4;
    const int rowA = blockIdx.x * 64 + w * 16 + m;
    const int rowc = rowA < N ? rowA : N - 1;
    s16x8 afr[4];
#pragma unroll
    for (int kc = 0; kc < 4; ++kc) {
        const int k0 = kc * 32 + quad * 8;
        if (!xf32) {
            afr[kc] = *(const s16x8*)((const __hip_bfloat16*)Xp + (long)rowc * 128 + k0);
        } else {
            const float* p = (const float*)Xp + (long)rowc * 128 + k0;
            s16x8 t;
#pragma unroll
            for (int j = 0; j < 8; ++j) t[j] = (short)f2bfu(p[j]);
            afr[kc] = t;
        }
    }
    const int rbase = blockIdx.x * 64 + w * 16 + quad * 4;
    float dv[4];
#pragma unroll
    for (int r = 0; r < 4; ++r) {
        int rr = min(rbase + r, N - 1);
        dv[r] = rsqrtf((float)(cnt[rr] + 1));
    }
#pragma unroll
    for (int ct = 0; ct < CT; ++ct) {
        f32x4 acc = {0.f, 0.f, 0.f, 0.f};
#pragma unroll
        for (int kc = 0; kc < 4; ++kc) {
            s16x8 bfr = *(const s16x8*)&Wt[(ct * 16 + m) * 136 + kc * 32 + quad * 8];
            acc = __builtin_amdgcn_mfma_f32_16x16x32_bf16(afr[kc], bfr, acc, 0, 0, 0);
        }
#pragma unroll
        for (int r = 0; r < 4; ++r) {
            int rr = rbase + r;
            if (rr < N) {
                long off;
                if (SPLIT) {
                    const int plane = ct / (CT / 2);
                    const int cp = (ct % (CT / 2)) * 16 + m;
                    off = (long)plane * N * (C / 2) + (long)rr * (C / 2) + cp;
                } else {
                    off = (long)rr * C + ct * 16 + m;
                }
                G[off] = __float2bfloat16(dv[r] * acc[r]);
            }
        }
    }
}

// Dual-plane gather, layer 1, ONE dispatch: blocks [0,half) do plane 0,
// [half,2*half) plane 1 (plane-0 first -> temporal L2 split). g UNscaled;
// dinv[s] applied per source.
__global__ __launch_bounds__(256) void k_gather1(const __hip_bfloat16* __restrict__ G,
                                                 const int* __restrict__ cnt,
                                                 const float* __restrict__ dinv,
                                                 const unsigned short* __restrict__ slots,
                                                 const int2* __restrict__ ovf2,
                                                 const int* __restrict__ ovf2cnt,
                                                 const void* __restrict__ b1,
                                                 __hip_bfloat16* __restrict__ h1,
                                                 const int* __restrict__ flags, int N) {
    const int half = gridDim.x >> 1;
    int bx = blockIdx.x;
    const int P = bx >= half ? 1 : 0;
    if (P) bx -= half;
    const __hip_bfloat16* Gp = G + (long)P * N * 64;
    const int tid = threadIdx.x;
    const int grp = tid >> 3, lane = tid & 7;
    const int node = bx * 32 + grp;
    if (node >= N) return;
    const int cd = cnt[node];
    const float wself = dinv[node];
    const int m = cd < CAP ? cd : CAP;
    const unsigned short* sl = slots + (long)node * CAP;
    float acc[8] = {0, 0, 0, 0, 0, 0, 0, 0};
    acc_fma(acc, ((const uint4*)(Gp + (long)node * 64))[lane], wself);   // self loop
    int i = 0;
    for (; i + 7 < m; i += 8) {
        int s0 = sl[i], s1 = sl[i + 1], s2 = sl[i + 2], s3 = sl[i + 3];
        int s4 = sl[i + 4], s5 = sl[i + 5], s6 = sl[i + 6], s7 = sl[i + 7];
        float w0 = dinv[s0], w1 = dinv[s1], w2 = dinv[s2], w3 = dinv[s3];
        float w4 = dinv[s4], w5 = dinv[s5], w6 = dinv[s6], w7 = dinv[s7];
        uint4 v0 = ((const uint4*)(Gp + (long)s0 * 64))[lane];
        uint4 v1 = ((const uint4*)(Gp + (long)s1 * 64))[lane];
        uint4 v2 = ((const uint4*)(Gp + (long)s2 * 64))[lane];
        uint4 v3 = ((const uint4*)(Gp + (long)s3 * 64))[lane];
        uint4 v4 = ((const uint4*)(Gp + (long)s4 * 64))[lane];
        uint4 v5 = ((const uint4*)(Gp + (long)s5 * 64))[lane];
        uint4 v6 = ((const uint4*)(Gp + (long)s6 * 64))[lane];
        uint4 v7 = ((const uint4*)(Gp + (long)s7 * 64))[lane];
        acc_fma(acc, v0, w0); acc_fma(acc, v1, w1); acc_fma(acc, v2, w2); acc_fma(acc, v3, w3);
        acc_fma(acc, v4, w4); acc_fma(acc, v5, w5); acc_fma(acc, v6, w6); acc_fma(acc, v7, w7);
    }
    for (; i + 3 < m; i += 4) {
        int s0 = sl[i], s1 = sl[i + 1], s2 = sl[i + 2], s3 = sl[i + 3];
        float w0 = dinv[s0], w1 = dinv[s1], w2 = dinv[s2], w3 = dinv[s3];
        uint4 v0 = ((const uint4*)(Gp + (long)s0 * 64))[lane];
        uint4 v1 = ((const uint4*)(Gp + (long)s1 * 64))[lane];
        uint4 v2 = ((const uint4*)(Gp + (long)s2 * 64))[lane];
        uint4 v3 = ((const uint4*)(Gp + (long)s3 * 64))[lane];
        acc_fma(acc, v0, w0); acc_fma(acc, v1, w1); acc_fma(acc, v2, w2); acc_fma(acc, v3, w3);
    }
    for (; i < m; ++i) {
        int s0 = sl[i];
        acc_fma(acc, ((const uint4*)(Gp + (long)s0 * 64))[lane], dinv[s0]);
    }
    if (cd > CAP) {
        int oc = *ovf2cnt; oc = oc < OVF_MAX ? oc : OVF_MAX;
        for (int j = 0; j < oc; ++j)
            if (ovf2[j].x == node) {
                int s0 = ovf2[j].y;
                acc_fma(acc, ((const uint4*)(Gp + (long)s0 * 64))[lane], dinv[s0]);
            }
    }
    const bool f32m = flags[0] != 0;
    const int c0 = P * 64 + lane * 8;
    float bv[8];
    if (f32m) {
        const float4* bp = (const float4*)((const float*)b1 + c0);
        float4 b0 = bp[0], b1v = bp[1];
        bv[0] = b0.x; bv[1] = b0.y; bv[2] = b0.z; bv[3] = b0.w;
        bv[4] = b1v.x; bv[5] = b1v.y; bv[6] = b1v.z; bv[7] = b1v.w;
    } else {
        uint4 b = *(const uint4*)((const __hip_bfloat16*)b1 + c0);
        bv[0] = lo2f(b.x); bv[1] = hi2f(b.x); bv[2] = lo2f(b.y); bv[3] = hi2f(b.y);
        bv[4] = lo2f(b.z); bv[5] = hi2f(b.z); bv[6] = lo2f(b.w); bv[7] = hi2f(b.w);
    }
    float o[8];
#pragma unroll
    for (int c = 0; c < 8; ++c) {
        float v = wself * acc[c] + bv[c];
        o[c] = v > 0.f ? v : 0.f;
    }
    uint4 pv = { pack2(o[0], o[1]), pack2(o[2], o[3]), pack2(o[4], o[5]), pack2(o[6], o[7]) };
    ((uint4*)(h1 + (long)node * 128 + P * 64))[lane] = pv;
}

// Full-row gather over pre-scaled G (layer 2 and fallback layer 1).
template<int F, int LAYER1, typename ST>
__global__ __launch_bounds__(256) void k_gather(const __hip_bfloat16* __restrict__ G,
                                                const int* __restrict__ cnt,
                                                const ST* __restrict__ slots,
                                                const int2* __restrict__ ovf2,
                                                const int* __restrict__ ovf2cnt,
                                                const void* __restrict__ bias,
                                                void* __restrict__ outp,
                                                const int* __restrict__ flags, int N) {
    constexpr int L = F / 8;
    constexpr int NODES = 256 / L;
    const int tid = threadIdx.x;
    const int grp = tid / L, lane = tid % L;
    const int node = blockIdx.x * NODES + grp;
    if (node >= N) return;
    const int cd = cnt[node];
    const float wself = rsqrtf((float)(cd + 1));
    const int m = cd < CAP ? cd : CAP;
    const ST* sl = slots + (long)node * CAP;
    float acc[8] = {0, 0, 0, 0, 0, 0, 0, 0};
    acc_add(acc, ((const uint4*)(G + (long)node * F))[lane]);
    int i = 0;
    for (; i + 7 < m; i += 8) {
        int s0 = sl[i], s1 = sl[i + 1], s2 = sl[i + 2], s3 = sl[i + 3];
        int s4 = sl[i + 4], s5 = sl[i + 5], s6 = sl[i + 6], s7 = sl[i + 7];
        uint4 v0 = ((const uint4*)(G + (long)s0 * F))[lane];
        uint4 v1 = ((const uint4*)(G + (long)s1 * F))[lane];
        uint4 v2 = ((const uint4*)(G + (long)s2 * F))[lane];
        uint4 v3 = ((const uint4*)(G + (long)s3 * F))[lane];
        uint4 v4 = ((const uint4*)(G + (long)s4 * F))[lane];
        uint4 v5 = ((const uint4*)(G + (long)s5 * F))[lane];
        uint4 v6 = ((const uint4*)(G + (long)s6 * F))[lane];
        uint4 v7 = ((const uint4*)(G + (long)s7 * F))[lane];
        acc_add(acc, v0); acc_add(acc, v1); acc_add(acc, v2); acc_add(acc, v3);
        acc_add(acc, v4); acc_add(acc, v5); acc_add(acc, v6); acc_add(acc, v7);
    }
    for (; i + 3 < m; i += 4) {
        int s0 = sl[i], s1 = sl[i + 1], s2 = sl[i + 2], s3 = sl[i + 3];
        uint4 v0 = ((const uint4*)(G + (long)s0 * F))[lane];
        uint4 v1 = ((const uint4*)(G + (long)s1 * F))[lane];
        uint4 v2 = ((const uint4*)(G + (long)s2 * F))[lane];
        uint4 v3 = ((const uint4*)(G + (long)s3 * F))[lane];
        acc_add(acc, v0); acc_add(acc, v1); acc_add(acc, v2); acc_add(acc, v3);
    }
    for (; i < m; ++i)
        acc_add(acc, ((const uint4*)(G + (long)sl[i] * F))[lane]);
    if (cd > CAP) {
        int oc = *ovf2cnt; oc = oc < OVF_MAX ? oc : OVF_MAX;
        for (int j = 0; j < oc; ++j)
            if (ovf2[j].x == node)
                acc_add(acc, ((const uint4*)(G + (long)ovf2[j].y * F))[lane]);
    }
    const bool f32m = flags[0] != 0;
    const int c0 = lane * 8;
    float bv[8];
    if (f32m) {
        const float4* bp = (const float4*)((const float*)bias + c0);
        float4 b0 = bp[0], b1 = bp[1];
        bv[0] = b0.x; bv[1] = b0.y; bv[2] = b0.z; bv[3] = b0.w;
        bv[4] = b1.x; bv[5] = b1.y; bv[6] = b1.z; bv[7] = b1.w;
    } else {
        uint4 b = *(const uint4*)((const __hip_bfloat16*)bias + c0);
        bv[0] = lo2f(b.x); bv[1] = hi2f(b.x); bv[2] = lo2f(b.y); bv[3] = hi2f(b.y);
        bv[4] = lo2f(b.z); bv[5] = hi2f(b.z); bv[6] = lo2f(b.w); bv[7] = hi2f(b.w);
    }
    float o[8];
#pragma unroll
    for (int c = 0; c < 8; ++c) {
        float v = wself * acc[c] + bv[c];
        o[c] = (LAYER1 && v < 0.f) ? 0.f : v;
    }
    if (LAYER1 || !f32m) {
        uint4 pv = { pack2(o[0], o[1]), pack2(o[2], o[3]), pack2(o[4], o[5]), pack2(o[6], o[7]) };
        ((uint4*)outp)[(long)node * L + lane] = pv;
    } else {
        float4* op = (float4*)((float*)outp + (long)node * F + c0);
        op[0] = make_float4(o[0], o[1], o[2], o[3]);
        op[1] = make_float4(o[4], o[5], o[6], o[7]);
    }
}

extern "C" void kernel_launch(void* const* d_in, const int* in_sizes, int n_in,
                              void* d_out, int out_size, void* d_ws, size_t ws_size,
                              hipStream_t stream) {
    const void* x  = d_in[0];
    const int*  ei = (const int*)d_in[1];
    const void* W1 = d_in[2];
    const void* b1 = d_in[3];
    const void* W2 = d_in[4];
    const void* b2 = d_in[5];

    const int N = in_sizes[0] / FIN;   // 50000
    const int E = in_sizes[1] / 2;     // 800000
    const int nbuk = (N + NPB - 1) / NPB;   // 511 (<=512 for u16 path)

    // ws layout (bytes), peak ~37.3MB:
    //   flags @0; gcur @4096 (512+2 ints)
    //   cnt @65536 (4N); dinv @266240 (4N)
    //   ovfA @524288; ovf2 @1048576
    //   slots @2097152 (u16 4.8MB / int 9.6MB)
    //   g @11730944 (12.8MB, 2 planes of N*64; g2 overlays)
    //   pairs @24530944 (6.28MB; h1 overlays after binB)
    char* ws = (char*)d_ws;
    int*   flags   = (int*)ws;
    int*   gcur    = (int*)(ws + 4096);
    int*   ovfAcnt = gcur + 512;
    int*   ovf2cnt = gcur + 513;
    int*   cnt     = (int*)(ws + 65536);
    float* dinv    = (float*)(ws + 266240);
    int2*  ovfA    = (int2*)(ws + 524288);
    int2*  ovf2    = (int2*)(ws + 1048576);
    unsigned short* slots16 = (unsigned short*)(ws + 2097152);
    int*   slots32 = (int*)(ws + 2097152);
    __hip_bfloat16* g  = (__hip_bfloat16*)(ws + 11730944);
    __hip_bfloat16* g2 = g;
    unsigned* pairs = (unsigned*)(ws + 24530944);
    __hip_bfloat16* h1 = (__hip_bfloat16*)(ws + 24530944);

    const int GB = (N + 63) / 64;
    const int AB = (E + 2047) / 2048;
    const int EB = (E + 255) / 256;

    if (N <= 65536 && nbuk <= 512) {
        k_detect<<<1, 256, 0, stream>>>((const unsigned*)x, ei, E, flags, gcur, cnt, N, 0);
        k_mega<<<GB + AB, 256, 34816, stream>>>(x, W1, ei, E, N, nbuk, GB,
                                                gcur, pairs, ovfA, ovfAcnt, g, flags);
        k_binB<<<nbuk, 256, 0, stream>>>(gcur, pairs, ovfA, ovfAcnt, cnt, dinv, slots16, ovf2, ovf2cnt, N);
        const int half = (N + 31) / 32;
        k_gather1<<<2 * half, 256, 0, stream>>>(g, cnt, dinv, slots16, ovf2, ovf2cnt, b1, h1, flags, N);
        k_gemm<4, 0><<<GB, 256, 0, stream>>>(h1, 0, W2, cnt, g2, flags, N);
        k_gather<64, 0, unsigned short><<<(N + 31) / 32, 256, 0, stream>>>(
            g2, cnt, slots16, ovf2, ovf2cnt, b2, d_out, flags, N);
    } else {
        k_detect<<<64, 256, 0, stream>>>((const unsigned*)x, ei, E, flags, gcur, cnt, N, 1);
        k_build_direct<<<EB, 256, 0, stream>>>(ei, E, N, cnt, slots32, ovf2, ovf2cnt, flags);
        k_gemm<8, 0><<<GB, 256, 0, stream>>>(x, 1, W1, cnt, g, flags, N);
        k_gather<128, 1, int><<<(N + 15) / 16, 256, 0, stream>>>(
            g, cnt, slots32, ovf2, ovf2cnt, b1, h1, flags, N);
        k_gemm<4, 0><<<GB, 256, 0, stream>>>(h1, 0, W2, cnt, g2, flags, N);
        k_gather<64, 0, int><<<(N + 31) / 32, 256, 0, stream>>>(
            g2, cnt, slots32, ovf2, ovf2cnt, b2, d_out, flags, N);
    }
}